// Round 4
// baseline (878.455 us; speedup 1.0000x reference)
//
#include <hip/hip_runtime.h>
#include <hip/hip_bf16.h>

#define B_ 4
#define S_ 2048
#define E_ 1024
#define H_ 16
#define D_ 64

typedef _Float16 f16;
typedef __attribute__((ext_vector_type(4))) float f32x4;
typedef __attribute__((ext_vector_type(8))) short bf16x8;
typedef __attribute__((ext_vector_type(8))) unsigned short u16x8;
typedef __attribute__((ext_vector_type(8))) _Float16 f16x8;
typedef __attribute__((ext_vector_type(4))) float float4v;

__device__ __forceinline__ unsigned short f2bf(float f) {
  union { float f; unsigned int u; } x; x.f = f;
  unsigned int u = x.u;
  u = (u + 0x7FFFu + ((u >> 16) & 1u)) >> 16;
  return (unsigned short)u;
}

#define MFMA_BF(a, b, c) __builtin_amdgcn_mfma_f32_16x16x32_bf16((a), (b), (c), 0, 0, 0)
#define MFMA_F16(a, b, c) __builtin_amdgcn_mfma_f32_16x16x32_f16((a), (b), (c), 0, 0, 0)

// fp32 [z][R][C] -> bf16 [z][C][R]
__global__ __launch_bounds__(256)
void transpose_convert(const float* __restrict__ src, unsigned short* __restrict__ dst,
                       int R, int C, float scale) {
  __shared__ unsigned short tile[64][65];
  const int rb = blockIdx.y * 64;
  const int cb = blockIdx.x * 64;
  const size_t mo = (size_t)blockIdx.z * (size_t)R * (size_t)C;
  const int t = threadIdx.x;
  const int r = t >> 2;
  const int c0 = (t & 3) * 16;
  const float* sp = src + mo + (size_t)(rb + r) * C + cb + c0;
#pragma unroll
  for (int j = 0; j < 16; j += 4) {
    float4v vv = *(const float4v*)(sp + j);
    tile[r][c0 + j + 0] = f2bf(vv[0] * scale);
    tile[r][c0 + j + 1] = f2bf(vv[1] * scale);
    tile[r][c0 + j + 2] = f2bf(vv[2] * scale);
    tile[r][c0 + j + 3] = f2bf(vv[3] * scale);
  }
  __syncthreads();
  u16x8 w0, w1;
#pragma unroll
  for (int j = 0; j < 8; ++j) w0[j] = tile[c0 + j][r];
#pragma unroll
  for (int j = 0; j < 8; ++j) w1[j] = tile[c0 + 8 + j][r];
  unsigned short* dp = dst + mo + (size_t)(cb + r) * R + rb + c0;
  *(u16x8*)(dp) = w0;
  *(u16x8*)(dp + 8) = w1;
}

// fp32 [z][R][C] -> f16 hi/lo [z][C][R] (2-way split, ~23-bit effective)
__global__ __launch_bounds__(256)
void transpose_split_f16(const float* __restrict__ src, f16* __restrict__ dhi,
                         f16* __restrict__ dlo, int R, int C, float scale) {
  __shared__ float tile[64][65];
  const int rb = blockIdx.y * 64;
  const int cb = blockIdx.x * 64;
  const size_t mo = (size_t)blockIdx.z * (size_t)R * (size_t)C;
  const int t = threadIdx.x;
  const int r = t >> 2;
  const int c0 = (t & 3) * 16;
  const float* sp = src + mo + (size_t)(rb + r) * C + cb + c0;
#pragma unroll
  for (int j = 0; j < 16; j += 4) {
    float4v vv = *(const float4v*)(sp + j);
    tile[r][c0 + j + 0] = vv[0] * scale;
    tile[r][c0 + j + 1] = vv[1] * scale;
    tile[r][c0 + j + 2] = vv[2] * scale;
    tile[r][c0 + j + 3] = vv[3] * scale;
  }
  __syncthreads();
  f16x8 h0, h1, l0, l1;
#pragma unroll
  for (int j = 0; j < 8; ++j) {
    float x = tile[c0 + j][r];
    f16 hi = (f16)x;
    h0[j] = hi; l0[j] = (f16)(x - (float)hi);
  }
#pragma unroll
  for (int j = 0; j < 8; ++j) {
    float x = tile[c0 + 8 + j][r];
    f16 hi = (f16)x;
    h1[j] = hi; l1[j] = (f16)(x - (float)hi);
  }
  const size_t o = mo + (size_t)(cb + r) * R + rb + c0;
  *(f16x8*)(dhi + o) = h0; *(f16x8*)(dhi + o + 8) = h1;
  *(f16x8*)(dlo + o) = l0; *(f16x8*)(dlo + o + 8) = l1;
}

// Q/K projection, split-f16 (3-term): out = X @ W[h], fp32-grade accuracy.
__global__ __launch_bounds__(256)
void proj_qk(const float* __restrict__ q, const float* __restrict__ k,
             const f16* __restrict__ Whi, const f16* __restrict__ Wlo,
             f16* __restrict__ out_hi, f16* __restrict__ out_lo) {
  __shared__ f16 Ah[128 * 32], Al[128 * 32];
  __shared__ f16 Bh[64 * 32], Bl[64 * 32];
  const int t = threadIdx.x;
  const int p = blockIdx.z >> 2;
  const int b = blockIdx.z & 3;
  const int h = blockIdx.y;
  const int s0 = blockIdx.x * 128;
  const float* X = p ? k : q;

  const int arow = t >> 1;
  const int ac0 = (t & 1) * 16;
  const float* aptr = X + ((size_t)b * S_ + s0 + arow) * E_ + ac0;

  const int brow = t >> 2;
  const int bc0 = (t & 3) * 8;
  const size_t wof = (((size_t)p * H_ + h) * D_ + brow) * E_ + bc0;

  const int w = t >> 6, l = t & 63, lr = l & 15, lg = l >> 4;

  f32x4 acc[2][4];
#pragma unroll
  for (int i = 0; i < 2; ++i)
#pragma unroll
    for (int c = 0; c < 4; ++c) acc[i][c] = (f32x4){0.f, 0.f, 0.f, 0.f};

  for (int e0 = 0; e0 < E_; e0 += 32) {
    __syncthreads();
    f16x8 h0, h1, l0, l1;
#pragma unroll
    for (int jj = 0; jj < 2; ++jj) {
      float4v va = *(const float4v*)(aptr + e0 + jj * 8);
      float4v vb = *(const float4v*)(aptr + e0 + jj * 8 + 4);
#pragma unroll
      for (int j = 0; j < 4; ++j) {
        f16 hi = (f16)va[j];
        (jj ? h1 : h0)[j] = hi;
        (jj ? l1 : l0)[j] = (f16)(va[j] - (float)hi);
      }
#pragma unroll
      for (int j = 0; j < 4; ++j) {
        f16 hi = (f16)vb[j];
        (jj ? h1 : h0)[4 + j] = hi;
        (jj ? l1 : l0)[4 + j] = (f16)(vb[j] - (float)hi);
      }
    }
    *(f16x8*)&Ah[arow * 32 + ac0] = h0; *(f16x8*)&Ah[arow * 32 + ac0 + 8] = h1;
    *(f16x8*)&Al[arow * 32 + ac0] = l0; *(f16x8*)&Al[arow * 32 + ac0 + 8] = l1;
    *(f16x8*)&Bh[brow * 32 + bc0] = *(const f16x8*)(Whi + wof + e0);
    *(f16x8*)&Bl[brow * 32 + bc0] = *(const f16x8*)(Wlo + wof + e0);
    __syncthreads();

    f16x8 ah0 = *(const f16x8*)&Ah[(w * 32 + lr) * 32 + lg * 8];
    f16x8 ah1 = *(const f16x8*)&Ah[(w * 32 + 16 + lr) * 32 + lg * 8];
    f16x8 al0 = *(const f16x8*)&Al[(w * 32 + lr) * 32 + lg * 8];
    f16x8 al1 = *(const f16x8*)&Al[(w * 32 + 16 + lr) * 32 + lg * 8];
#pragma unroll
    for (int c = 0; c < 4; ++c) {
      f16x8 bh = *(const f16x8*)&Bh[(c * 16 + lr) * 32 + lg * 8];
      f16x8 bl = *(const f16x8*)&Bl[(c * 16 + lr) * 32 + lg * 8];
      acc[0][c] = MFMA_F16(ah0, bh, acc[0][c]);
      acc[0][c] = MFMA_F16(ah0, bl, acc[0][c]);
      acc[0][c] = MFMA_F16(al0, bh, acc[0][c]);
      acc[1][c] = MFMA_F16(ah1, bh, acc[1][c]);
      acc[1][c] = MFMA_F16(ah1, bl, acc[1][c]);
      acc[1][c] = MFMA_F16(al1, bh, acc[1][c]);
    }
  }

  const size_t ob = (((size_t)p * B_ + b) * H_ + h) * (size_t)S_ * D_;
#pragma unroll
  for (int i = 0; i < 2; ++i)
#pragma unroll
    for (int c = 0; c < 4; ++c)
#pragma unroll
      for (int r = 0; r < 4; ++r) {
        const int row = w * 32 + i * 16 + lg * 4 + r;
        const int col = c * 16 + lr;
        float x = acc[i][c][r];
        f16 hi = (f16)x;
        out_hi[ob + (size_t)(s0 + row) * D_ + col] = hi;
        out_lo[ob + (size_t)(s0 + row) * D_ + col] = (f16)(x - (float)hi);
      }
}

// V projection, bf16 MFMA; output f16 TRANSPOSED: vht[b][h][d][s].
__global__ __launch_bounds__(256)
void proj_v(const float* __restrict__ v, const unsigned short* __restrict__ Wt,
            f16* __restrict__ vht) {
  // 17408 B: main loop uses As(8KB)+Bs(4KB); epilogue reuses all for the
  // 64(d) x 128(s) transpose at stride 136 (64*136*2B = 17408 B).
  __shared__ unsigned short sm[8704];
  unsigned short* As = sm;
  unsigned short* Bs = sm + 4096;
  const int t = threadIdx.x;
  const int b = blockIdx.z;
  const int h = blockIdx.y;
  const int s0 = blockIdx.x * 128;

  const int arow = t >> 1;
  const int ac0 = (t & 1) * 16;
  const float* aptr = v + ((size_t)b * S_ + s0 + arow) * E_ + ac0;

  const int brow = t >> 2;
  const int bc0 = (t & 3) * 8;
  const unsigned short* bptr = Wt + ((size_t)h * D_ + brow) * E_ + bc0;

  const int w = t >> 6, l = t & 63, lr = l & 15, lg = l >> 4;

  f32x4 acc[2][4];
#pragma unroll
  for (int i = 0; i < 2; ++i)
#pragma unroll
    for (int c = 0; c < 4; ++c) acc[i][c] = (f32x4){0.f, 0.f, 0.f, 0.f};

  for (int e0 = 0; e0 < E_; e0 += 32) {
    __syncthreads();
    float4v v0 = *(const float4v*)(aptr + e0);
    float4v v1 = *(const float4v*)(aptr + e0 + 4);
    float4v v2 = *(const float4v*)(aptr + e0 + 8);
    float4v v3 = *(const float4v*)(aptr + e0 + 12);
    u16x8 w0, w1;
#pragma unroll
    for (int j = 0; j < 4; ++j) { w0[j] = f2bf(v0[j]); w0[4 + j] = f2bf(v1[j]); }
#pragma unroll
    for (int j = 0; j < 4; ++j) { w1[j] = f2bf(v2[j]); w1[4 + j] = f2bf(v3[j]); }
    *(u16x8*)&As[arow * 32 + ac0] = w0;
    *(u16x8*)&As[arow * 32 + ac0 + 8] = w1;
    *(u16x8*)&Bs[brow * 32 + bc0] = *(const u16x8*)(bptr + e0);
    __syncthreads();

    bf16x8 af0 = *(const bf16x8*)&As[(w * 32 + lr) * 32 + lg * 8];
    bf16x8 af1 = *(const bf16x8*)&As[(w * 32 + 16 + lr) * 32 + lg * 8];
#pragma unroll
    for (int c = 0; c < 4; ++c) {
      bf16x8 bf = *(const bf16x8*)&Bs[(c * 16 + lr) * 32 + lg * 8];
      acc[0][c] = MFMA_BF(af0, bf, acc[0][c]);
      acc[1][c] = MFMA_BF(af1, bf, acc[1][c]);
    }
  }

  // Epilogue: LDS transpose Td[d][s] (stride 136), coalesced f16 write.
  const size_t bhD = ((size_t)b * H_ + h) * D_;
  __syncthreads();
  f16* Td = (f16*)sm;  // 64 x 136 f16 = 17408 B
#pragma unroll
  for (int i = 0; i < 2; ++i)
#pragma unroll
    for (int c = 0; c < 4; ++c)
#pragma unroll
      for (int r = 0; r < 4; ++r) {
        const int srow = w * 32 + i * 16 + lg * 4 + r;   // 0..127
        Td[(c * 16 + lr) * 136 + srow] = (f16)acc[i][c][r];
      }
  __syncthreads();
  const int dd = t >> 2;           // 0..63
  const int sc2 = (t & 3) * 32;    // 0..96
  f16* vp = vht + (bhD + dd) * S_ + s0 + sc2;
#pragma unroll
  for (int j = 0; j < 4; ++j)
    *(f16x8*)(vp + j * 8) = *(const f16x8*)&Td[dd * 136 + sc2 + j * 8];
}

// Causal flash attention v2: QBLK=128 (4 waves x 32 rows), KVBLK=64,
// XOR-swizzled LDS (K hi/lo, V^T, P), QK^T split-f16, PV f16.
__global__ __launch_bounds__(256, 3)
void attn_kernel(const f16* __restrict__ qhh, const f16* __restrict__ qhl,
                 const f16* __restrict__ khh, const f16* __restrict__ khl,
                 const f16* __restrict__ vht, unsigned short* __restrict__ ao) {
  __shared__ f16 Ksh[64 * 64];        // [kv][d], 128B rows, swizzled
  __shared__ f16 Ksl[64 * 64];
  __shared__ f16 Vts[64 * 64];        // [d][kv], 128B rows, swizzled
  __shared__ f16 Pls[4][32 * 64];     // per-wave [q][kv], swizzled
  const int t = threadIdx.x;
  const int b = blockIdx.z, h = blockIdx.y;
  const int q0 = blockIdx.x * 128;
  const int w = t >> 6, l = t & 63, lr = l & 15, lg = l >> 4;
  const size_t bh = ((size_t)b * H_ + h) * S_;
  const size_t bhD = ((size_t)b * H_ + h) * D_;

  // Q fragments in registers (hi/lo), rows w*32 + i*16 + lr.
  f16x8 qfh[2][2], qfl[2][2];
#pragma unroll
  for (int i = 0; i < 2; ++i) {
    const size_t qo = (bh + q0 + w * 32 + i * 16 + lr) * D_;
#pragma unroll
    for (int hf = 0; hf < 2; ++hf) {
      qfh[i][hf] = *(const f16x8*)(qhh + qo + hf * 32 + lg * 8);
      qfl[i][hf] = *(const f16x8*)(qhl + qo + hf * 32 + lg * 8);
    }
  }

  f32x4 acc[2][4];
#pragma unroll
  for (int i = 0; i < 2; ++i)
#pragma unroll
    for (int c = 0; c < 4; ++c) acc[i][c] = (f32x4){0.f, 0.f, 0.f, 0.f};
  float mx[2][4], ls[2][4];
#pragma unroll
  for (int i = 0; i < 2; ++i)
#pragma unroll
    for (int r = 0; r < 4; ++r) { mx[i][r] = -3.0e38f; ls[i][r] = 0.f; }

  const int wmax = q0 + w * 32 + 31;  // last q-row this wave owns
  const int nkt = q0 / 64 + 2;
  for (int kt = 0; kt < nkt; ++kt) {
    const int kt0 = kt * 64;
    __syncthreads();
    // Stage K hi/lo + V^T, 2 chunks each per thread, swizzled LDS writes.
    {
      const f16* kbh = khh + (bh + kt0) * D_;
      const f16* kbl = khl + (bh + kt0) * D_;
      const f16* vb = vht + bhD * S_ + kt0;
#pragma unroll
      for (int j = 0; j < 2; ++j) {
        const int idx = t + j * 256;
        const int row = idx >> 3, ch = idx & 7;
        const int off = (ch * 16) ^ ((row & 7) << 4);
        *(f16x8*)((char*)Ksh + row * 128 + off) = *(const f16x8*)(kbh + row * 64 + ch * 8);
        *(f16x8*)((char*)Ksl + row * 128 + off) = *(const f16x8*)(kbl + row * 64 + ch * 8);
        *(f16x8*)((char*)Vts + row * 128 + off) = *(const f16x8*)(vb + (size_t)row * S_ + ch * 8);
      }
    }
    __syncthreads();

    if (kt0 > wmax) continue;  // tile fully masked for this wave (uniform)

    // QK^T: 48 MFMA per wave (2 i-groups x 4 n-tiles x 6 split-terms).
    f32x4 sc[2][4];
#pragma unroll
    for (int n = 0; n < 4; ++n) {
      const int krow = n * 16 + lr;
      const int sw = (krow & 7) << 4;
      const char* kb = (const char*)Ksh + krow * 128;
      const char* kbl2 = (const char*)Ksl + krow * 128;
      f16x8 kh0 = *(const f16x8*)(kb + ((lg * 16) ^ sw));
      f16x8 kh1 = *(const f16x8*)(kb + ((64 + lg * 16) ^ sw));
      f16x8 kl0 = *(const f16x8*)(kbl2 + ((lg * 16) ^ sw));
      f16x8 kl1 = *(const f16x8*)(kbl2 + ((64 + lg * 16) ^ sw));
#pragma unroll
      for (int i = 0; i < 2; ++i) {
        f32x4 z = (f32x4){0.f, 0.f, 0.f, 0.f};
        z = MFMA_F16(qfh[i][0], kh0, z);
        z = MFMA_F16(qfh[i][1], kh1, z);
        z = MFMA_F16(qfh[i][0], kl0, z);
        z = MFMA_F16(qfh[i][1], kl1, z);
        z = MFMA_F16(qfl[i][0], kh0, z);
        z = MFMA_F16(qfl[i][1], kh1, z);
        sc[i][n] = z;
      }
    }

    // Online softmax per i-group; write P (f16) to per-wave swizzled LDS.
#pragma unroll
    for (int i = 0; i < 2; ++i) {
      const int qbase = q0 + w * 32 + i * 16;
      const bool full = (kt0 + 63 <= qbase);
#pragma unroll
      for (int r = 0; r < 4; ++r) {
        const int qrow = qbase + lg * 4 + r;
        float v0 = sc[i][0][r], v1 = sc[i][1][r], v2 = sc[i][2][r], v3 = sc[i][3][r];
        if (!full) {
          v0 = (kt0 + 0 + lr <= qrow) ? v0 : -3.0e38f;
          v1 = (kt0 + 16 + lr <= qrow) ? v1 : -3.0e38f;
          v2 = (kt0 + 32 + lr <= qrow) ? v2 : -3.0e38f;
          v3 = (kt0 + 48 + lr <= qrow) ? v3 : -3.0e38f;
        }
        float tm = fmaxf(fmaxf(v0, v1), fmaxf(v2, v3));
        tm = fmaxf(tm, __shfl_xor(tm, 1));
        tm = fmaxf(tm, __shfl_xor(tm, 2));
        tm = fmaxf(tm, __shfl_xor(tm, 4));
        tm = fmaxf(tm, __shfl_xor(tm, 8));
        const float mn = fmaxf(mx[i][r], tm);
        const float corr = __expf(mx[i][r] - mn);
        mx[i][r] = mn;
        float p0 = __expf(v0 - mn), p1 = __expf(v1 - mn);
        float p2 = __expf(v2 - mn), p3 = __expf(v3 - mn);
        float ps = (p0 + p1) + (p2 + p3);
        ps += __shfl_xor(ps, 1);
        ps += __shfl_xor(ps, 2);
        ps += __shfl_xor(ps, 4);
        ps += __shfl_xor(ps, 8);
        ls[i][r] = ls[i][r] * corr + ps;
#pragma unroll
        for (int c = 0; c < 4; ++c) acc[i][c][r] *= corr;
        const int qi = i * 16 + lg * 4 + r;
        char* pb = (char*)&Pls[w][0] + qi * 128;
        const int sw2 = (qi & 7) << 4;
        *(f16*)(pb + ((0 + lr * 2) ^ sw2)) = (f16)p0;
        *(f16*)(pb + ((32 + lr * 2) ^ sw2)) = (f16)p1;
        *(f16*)(pb + ((64 + lr * 2) ^ sw2)) = (f16)p2;
        *(f16*)(pb + ((96 + lr * 2) ^ sw2)) = (f16)p3;
      }
    }

    // PV: 16 MFMA per wave. P is per-wave (no barrier needed).
#pragma unroll
    for (int ks = 0; ks < 2; ++ks) {
      const int co = (ks * 64 + lg * 16);
      f16x8 pf0 = *(const f16x8*)((const char*)&Pls[w][0] + lr * 128 + (co ^ ((lr & 7) << 4)));
      f16x8 pf1 = *(const f16x8*)((const char*)&Pls[w][0] + (16 + lr) * 128 + (co ^ ((lr & 7) << 4)));
#pragma unroll
      for (int c = 0; c < 4; ++c) {
        const int vr = c * 16 + lr;
        f16x8 vf = *(const f16x8*)((const char*)Vts + vr * 128 + (co ^ ((vr & 7) << 4)));
        acc[0][c] = MFMA_F16(pf0, vf, acc[0][c]);
        acc[1][c] = MFMA_F16(pf1, vf, acc[1][c]);
      }
    }
  }

  // Epilogue: ao[b][s][h][d] bf16.
#pragma unroll
  for (int i = 0; i < 2; ++i)
#pragma unroll
    for (int r = 0; r < 4; ++r) {
      const float inv = 1.0f / ls[i][r];
      const size_t s = q0 + w * 32 + i * 16 + lg * 4 + r;
      const size_t o = ((size_t)b * S_ + s) * (H_ * D_) + (size_t)h * D_;
#pragma unroll
      for (int c = 0; c < 4; ++c)
        ao[o + c * 16 + lr] = f2bf(acc[i][c][r] * inv);
    }
}

// Output projection: d_out[m][n] = sum_k ao[m][k] * Wo[k][n] (Wot = Wo^T bf16)
__global__ __launch_bounds__(256)
void out_gemm(const unsigned short* __restrict__ A, const unsigned short* __restrict__ Bt,
              float* __restrict__ Cout) {
  __shared__ unsigned short As[128 * 32];
  __shared__ unsigned short Bs[64 * 32];
  const int t = threadIdx.x;
  const int m0 = blockIdx.x * 128;
  const int n0 = blockIdx.y * 64;
  const int arow = t >> 1, ac0 = (t & 1) * 16;
  const unsigned short* aptr = A + (size_t)(m0 + arow) * 1024 + ac0;
  const int brow = t >> 2, bc0 = (t & 3) * 8;
  const unsigned short* bptr = Bt + (size_t)(n0 + brow) * 1024 + bc0;
  const int w = t >> 6, l = t & 63, lr = l & 15, lg = l >> 4;

  f32x4 acc[2][4];
#pragma unroll
  for (int i = 0; i < 2; ++i)
#pragma unroll
    for (int c = 0; c < 4; ++c) acc[i][c] = (f32x4){0.f, 0.f, 0.f, 0.f};

  for (int k0 = 0; k0 < 1024; k0 += 32) {
    __syncthreads();
    *(u16x8*)&As[arow * 32 + ac0] = *(const u16x8*)(aptr + k0);
    *(u16x8*)&As[arow * 32 + ac0 + 8] = *(const u16x8*)(aptr + k0 + 8);
    *(u16x8*)&Bs[brow * 32 + bc0] = *(const u16x8*)(bptr + k0);
    __syncthreads();

    bf16x8 af0 = *(const bf16x8*)&As[(w * 32 + lr) * 32 + lg * 8];
    bf16x8 af1 = *(const bf16x8*)&As[(w * 32 + 16 + lr) * 32 + lg * 8];
#pragma unroll
    for (int c = 0; c < 4; ++c) {
      bf16x8 bf = *(const bf16x8*)&Bs[(c * 16 + lr) * 32 + lg * 8];
      acc[0][c] = MFMA_BF(af0, bf, acc[0][c]);
      acc[1][c] = MFMA_BF(af1, bf, acc[1][c]);
    }
  }

#pragma unroll
  for (int i = 0; i < 2; ++i)
#pragma unroll
    for (int c = 0; c < 4; ++c)
#pragma unroll
      for (int r = 0; r < 4; ++r) {
        const int row = m0 + w * 32 + i * 16 + lg * 4 + r;
        const int col = n0 + c * 16 + lr;
        Cout[(size_t)row * 1024 + col] = acc[i][c][r];
      }
}

extern "C" void kernel_launch(void* const* d_in, const int* in_sizes, int n_in,
                              void* d_out, int out_size, void* d_ws, size_t ws_size,
                              hipStream_t stream) {
  const float* q = (const float*)d_in[0];
  const float* k = (const float*)d_in[1];
  const float* v = (const float*)d_in[2];
  const float* Wq = (const float*)d_in[3];
  const float* Wk = (const float*)d_in[4];
  const float* Wv = (const float*)d_in[5];
  const float* Wo = (const float*)d_in[6];

  const size_t NBH = (size_t)B_ * H_ * S_ * D_;   // 8388608
  const size_t WSZ = (size_t)H_ * D_ * E_;        // 1048576

  char* wsb = (char*)d_ws;
  f16* qk_hi = (f16*)wsb;                          // [2][B][H][S][D]
  f16* qk_lo = qk_hi + 2 * NBH;                    // [2][B][H][S][D]
  f16* vht = qk_lo + 2 * NBH;                      // [B][H][D][S] (transposed)
  unsigned short* ao = (unsigned short*)(vht + NBH); // [B][S][H][D]
  f16* Wqk_hi = (f16*)(ao + NBH);                  // [2][H][D][E]
  f16* Wqk_lo = Wqk_hi + 2 * WSZ;
  unsigned short* Wvt = (unsigned short*)(Wqk_lo + 2 * WSZ); // [H][D][E]
  unsigned short* Wot = Wvt + WSZ;                 // [E][H*D]

  dim3 blk(256);
  // Weight prep (x8 quirk folded into Wq, exact).
  transpose_split_f16<<<dim3(1, 16, 16), blk, 0, stream>>>(Wq, Wqk_hi, Wqk_lo, E_, D_, 8.0f);
  transpose_split_f16<<<dim3(1, 16, 16), blk, 0, stream>>>(Wk, Wqk_hi + WSZ, Wqk_lo + WSZ, E_, D_, 1.0f);
  transpose_convert<<<dim3(1, 16, 16), blk, 0, stream>>>(Wv, Wvt, E_, D_, 1.0f);
  transpose_convert<<<dim3(16, 16, 1), blk, 0, stream>>>(Wo, Wot, E_, E_, 1.0f);
  // Projections.
  proj_qk<<<dim3(S_ / 128, H_, 8), blk, 0, stream>>>(q, k, Wqk_hi, Wqk_lo, qk_hi, qk_lo);
  proj_v<<<dim3(S_ / 128, H_, B_), blk, 0, stream>>>(v, Wvt, vht);
  // Attention (QBLK=128, KVBLK=64).
  attn_kernel<<<dim3(S_ / 128, H_, B_), blk, 0, stream>>>(
      qk_hi, qk_lo, qk_hi + NBH, qk_lo + NBH, vht, ao);
  // Output projection.
  out_gemm<<<dim3((B_ * S_) / 128, E_ / 64), blk, 0, stream>>>(ao, Wot, (float*)d_out);
}

// Round 6
// 515.495 us; speedup vs baseline: 1.7041x; 1.7041x over previous
//
#include <hip/hip_runtime.h>
#include <hip/hip_bf16.h>

#define B_ 4
#define S_ 2048
#define E_ 1024
#define H_ 16
#define D_ 64

typedef _Float16 f16;
typedef __attribute__((ext_vector_type(4))) float f32x4;
typedef __attribute__((ext_vector_type(8))) short bf16x8;
typedef __attribute__((ext_vector_type(8))) unsigned short u16x8;
typedef __attribute__((ext_vector_type(8))) _Float16 f16x8;
typedef __attribute__((ext_vector_type(4))) float float4v;

__device__ __forceinline__ unsigned short f2bf(float f) {
  union { float f; unsigned int u; } x; x.f = f;
  unsigned int u = x.u;
  u = (u + 0x7FFFu + ((u >> 16) & 1u)) >> 16;
  return (unsigned short)u;
}

#define MFMA_BF(a, b, c) __builtin_amdgcn_mfma_f32_16x16x32_bf16((a), (b), (c), 0, 0, 0)
#define MFMA_F16(a, b, c) __builtin_amdgcn_mfma_f32_16x16x32_f16((a), (b), (c), 0, 0, 0)

// fp32 [z][R][C] -> bf16 [z][C][R]
__global__ __launch_bounds__(256)
void transpose_convert(const float* __restrict__ src, unsigned short* __restrict__ dst,
                       int R, int C, float scale) {
  __shared__ unsigned short tile[64][65];
  const int rb = blockIdx.y * 64;
  const int cb = blockIdx.x * 64;
  const size_t mo = (size_t)blockIdx.z * (size_t)R * (size_t)C;
  const int t = threadIdx.x;
  const int r = t >> 2;
  const int c0 = (t & 3) * 16;
  const float* sp = src + mo + (size_t)(rb + r) * C + cb + c0;
#pragma unroll
  for (int j = 0; j < 16; j += 4) {
    float4v vv = *(const float4v*)(sp + j);
    tile[r][c0 + j + 0] = f2bf(vv[0] * scale);
    tile[r][c0 + j + 1] = f2bf(vv[1] * scale);
    tile[r][c0 + j + 2] = f2bf(vv[2] * scale);
    tile[r][c0 + j + 3] = f2bf(vv[3] * scale);
  }
  __syncthreads();
  u16x8 w0, w1;
#pragma unroll
  for (int j = 0; j < 8; ++j) w0[j] = tile[c0 + j][r];
#pragma unroll
  for (int j = 0; j < 8; ++j) w1[j] = tile[c0 + 8 + j][r];
  unsigned short* dp = dst + mo + (size_t)(cb + r) * R + rb + c0;
  *(u16x8*)(dp) = w0;
  *(u16x8*)(dp + 8) = w1;
}

// fp32 [z][R][C] -> f16 hi/lo [z][C][R] (2-way split, ~23-bit effective)
__global__ __launch_bounds__(256)
void transpose_split_f16(const float* __restrict__ src, f16* __restrict__ dhi,
                         f16* __restrict__ dlo, int R, int C, float scale) {
  __shared__ float tile[64][65];
  const int rb = blockIdx.y * 64;
  const int cb = blockIdx.x * 64;
  const size_t mo = (size_t)blockIdx.z * (size_t)R * (size_t)C;
  const int t = threadIdx.x;
  const int r = t >> 2;
  const int c0 = (t & 3) * 16;
  const float* sp = src + mo + (size_t)(rb + r) * C + cb + c0;
#pragma unroll
  for (int j = 0; j < 16; j += 4) {
    float4v vv = *(const float4v*)(sp + j);
    tile[r][c0 + j + 0] = vv[0] * scale;
    tile[r][c0 + j + 1] = vv[1] * scale;
    tile[r][c0 + j + 2] = vv[2] * scale;
    tile[r][c0 + j + 3] = vv[3] * scale;
  }
  __syncthreads();
  f16x8 h0, h1, l0, l1;
#pragma unroll
  for (int j = 0; j < 8; ++j) {
    float x = tile[c0 + j][r];
    f16 hi = (f16)x;
    h0[j] = hi; l0[j] = (f16)(x - (float)hi);
  }
#pragma unroll
  for (int j = 0; j < 8; ++j) {
    float x = tile[c0 + 8 + j][r];
    f16 hi = (f16)x;
    h1[j] = hi; l1[j] = (f16)(x - (float)hi);
  }
  const size_t o = mo + (size_t)(cb + r) * R + rb + c0;
  *(f16x8*)(dhi + o) = h0; *(f16x8*)(dhi + o + 8) = h1;
  *(f16x8*)(dlo + o) = l0; *(f16x8*)(dlo + o + 8) = l1;
}

// Q/K projection, split-f16 (3-term): out = X @ W[h], fp32-grade accuracy.
__global__ __launch_bounds__(256)
void proj_qk(const float* __restrict__ q, const float* __restrict__ k,
             const f16* __restrict__ Whi, const f16* __restrict__ Wlo,
             f16* __restrict__ out_hi, f16* __restrict__ out_lo) {
  __shared__ f16 Ah[128 * 32], Al[128 * 32];
  __shared__ f16 Bh[64 * 32], Bl[64 * 32];
  const int t = threadIdx.x;
  const int p = blockIdx.z >> 2;
  const int b = blockIdx.z & 3;
  const int h = blockIdx.y;
  const int s0 = blockIdx.x * 128;
  const float* X = p ? k : q;

  const int arow = t >> 1;
  const int ac0 = (t & 1) * 16;
  const float* aptr = X + ((size_t)b * S_ + s0 + arow) * E_ + ac0;

  const int brow = t >> 2;
  const int bc0 = (t & 3) * 8;
  const size_t wof = (((size_t)p * H_ + h) * D_ + brow) * E_ + bc0;

  const int w = t >> 6, l = t & 63, lr = l & 15, lg = l >> 4;

  f32x4 acc[2][4];
#pragma unroll
  for (int i = 0; i < 2; ++i)
#pragma unroll
    for (int c = 0; c < 4; ++c) acc[i][c] = (f32x4){0.f, 0.f, 0.f, 0.f};

  for (int e0 = 0; e0 < E_; e0 += 32) {
    __syncthreads();
    f16x8 h0, h1, l0, l1;
#pragma unroll
    for (int jj = 0; jj < 2; ++jj) {
      float4v va = *(const float4v*)(aptr + e0 + jj * 8);
      float4v vb = *(const float4v*)(aptr + e0 + jj * 8 + 4);
#pragma unroll
      for (int j = 0; j < 4; ++j) {
        f16 hi = (f16)va[j];
        (jj ? h1 : h0)[j] = hi;
        (jj ? l1 : l0)[j] = (f16)(va[j] - (float)hi);
      }
#pragma unroll
      for (int j = 0; j < 4; ++j) {
        f16 hi = (f16)vb[j];
        (jj ? h1 : h0)[4 + j] = hi;
        (jj ? l1 : l0)[4 + j] = (f16)(vb[j] - (float)hi);
      }
    }
    *(f16x8*)&Ah[arow * 32 + ac0] = h0; *(f16x8*)&Ah[arow * 32 + ac0 + 8] = h1;
    *(f16x8*)&Al[arow * 32 + ac0] = l0; *(f16x8*)&Al[arow * 32 + ac0 + 8] = l1;
    *(f16x8*)&Bh[brow * 32 + bc0] = *(const f16x8*)(Whi + wof + e0);
    *(f16x8*)&Bl[brow * 32 + bc0] = *(const f16x8*)(Wlo + wof + e0);
    __syncthreads();

    f16x8 ah0 = *(const f16x8*)&Ah[(w * 32 + lr) * 32 + lg * 8];
    f16x8 ah1 = *(const f16x8*)&Ah[(w * 32 + 16 + lr) * 32 + lg * 8];
    f16x8 al0 = *(const f16x8*)&Al[(w * 32 + lr) * 32 + lg * 8];
    f16x8 al1 = *(const f16x8*)&Al[(w * 32 + 16 + lr) * 32 + lg * 8];
#pragma unroll
    for (int c = 0; c < 4; ++c) {
      f16x8 bh = *(const f16x8*)&Bh[(c * 16 + lr) * 32 + lg * 8];
      f16x8 bl = *(const f16x8*)&Bl[(c * 16 + lr) * 32 + lg * 8];
      acc[0][c] = MFMA_F16(ah0, bh, acc[0][c]);
      acc[0][c] = MFMA_F16(ah0, bl, acc[0][c]);
      acc[0][c] = MFMA_F16(al0, bh, acc[0][c]);
      acc[1][c] = MFMA_F16(ah1, bh, acc[1][c]);
      acc[1][c] = MFMA_F16(ah1, bl, acc[1][c]);
      acc[1][c] = MFMA_F16(al1, bh, acc[1][c]);
    }
  }

  const size_t ob = (((size_t)p * B_ + b) * H_ + h) * (size_t)S_ * D_;
#pragma unroll
  for (int i = 0; i < 2; ++i)
#pragma unroll
    for (int c = 0; c < 4; ++c)
#pragma unroll
      for (int r = 0; r < 4; ++r) {
        const int row = w * 32 + i * 16 + lg * 4 + r;
        const int col = c * 16 + lr;
        float x = acc[i][c][r];
        f16 hi = (f16)x;
        out_hi[ob + (size_t)(s0 + row) * D_ + col] = hi;
        out_lo[ob + (size_t)(s0 + row) * D_ + col] = (f16)(x - (float)hi);
      }
}

// V projection, bf16 MFMA; output f16 TRANSPOSED: vht[b][h][d][s].
__global__ __launch_bounds__(256)
void proj_v(const float* __restrict__ v, const unsigned short* __restrict__ Wt,
            f16* __restrict__ vht) {
  // 17408 B: main loop uses As(8KB)+Bs(4KB); epilogue reuses all for the
  // 64(d) x 128(s) transpose at stride 136 (64*136*2B = 17408 B).
  __shared__ unsigned short sm[8704];
  unsigned short* As = sm;
  unsigned short* Bs = sm + 4096;
  const int t = threadIdx.x;
  const int b = blockIdx.z;
  const int h = blockIdx.y;
  const int s0 = blockIdx.x * 128;

  const int arow = t >> 1;
  const int ac0 = (t & 1) * 16;
  const float* aptr = v + ((size_t)b * S_ + s0 + arow) * E_ + ac0;

  const int brow = t >> 2;
  const int bc0 = (t & 3) * 8;
  const unsigned short* bptr = Wt + ((size_t)h * D_ + brow) * E_ + bc0;

  const int w = t >> 6, l = t & 63, lr = l & 15, lg = l >> 4;

  f32x4 acc[2][4];
#pragma unroll
  for (int i = 0; i < 2; ++i)
#pragma unroll
    for (int c = 0; c < 4; ++c) acc[i][c] = (f32x4){0.f, 0.f, 0.f, 0.f};

  for (int e0 = 0; e0 < E_; e0 += 32) {
    __syncthreads();
    float4v v0 = *(const float4v*)(aptr + e0);
    float4v v1 = *(const float4v*)(aptr + e0 + 4);
    float4v v2 = *(const float4v*)(aptr + e0 + 8);
    float4v v3 = *(const float4v*)(aptr + e0 + 12);
    u16x8 w0, w1;
#pragma unroll
    for (int j = 0; j < 4; ++j) { w0[j] = f2bf(v0[j]); w0[4 + j] = f2bf(v1[j]); }
#pragma unroll
    for (int j = 0; j < 4; ++j) { w1[j] = f2bf(v2[j]); w1[4 + j] = f2bf(v3[j]); }
    *(u16x8*)&As[arow * 32 + ac0] = w0;
    *(u16x8*)&As[arow * 32 + ac0 + 8] = w1;
    *(u16x8*)&Bs[brow * 32 + bc0] = *(const u16x8*)(bptr + e0);
    __syncthreads();

    bf16x8 af0 = *(const bf16x8*)&As[(w * 32 + lr) * 32 + lg * 8];
    bf16x8 af1 = *(const bf16x8*)&As[(w * 32 + 16 + lr) * 32 + lg * 8];
#pragma unroll
    for (int c = 0; c < 4; ++c) {
      bf16x8 bf = *(const bf16x8*)&Bs[(c * 16 + lr) * 32 + lg * 8];
      acc[0][c] = MFMA_BF(af0, bf, acc[0][c]);
      acc[1][c] = MFMA_BF(af1, bf, acc[1][c]);
    }
  }

  // Epilogue: LDS transpose Td[d][s] (stride 136), coalesced f16 write.
  const size_t bhD = ((size_t)b * H_ + h) * D_;
  __syncthreads();
  f16* Td = (f16*)sm;  // 64 x 136 f16 = 17408 B
#pragma unroll
  for (int i = 0; i < 2; ++i)
#pragma unroll
    for (int c = 0; c < 4; ++c)
#pragma unroll
      for (int r = 0; r < 4; ++r) {
        const int srow = w * 32 + i * 16 + lg * 4 + r;   // 0..127
        Td[(c * 16 + lr) * 136 + srow] = (f16)acc[i][c][r];
      }
  __syncthreads();
  const int dd = t >> 2;           // 0..63
  const int sc2 = (t & 3) * 32;    // 0..96
  f16* vp = vht + (bhD + dd) * S_ + s0 + sc2;
#pragma unroll
  for (int j = 0; j < 4; ++j)
    *(f16x8*)(vp + j * 8) = *(const f16x8*)&Td[dd * 136 + sc2 + j * 8];
}

// Causal flash attention v3: paired q-tiles (x, 15-x) for perfect causal
// balance; double-buffered K/V staging (prefetch to regs, write after
// compute); QBLK=128 (4 waves x 32 rows), KVBLK=64, XOR-swizzled LDS.
__global__ __launch_bounds__(256, 2)
void attn_kernel(const f16* __restrict__ qhh, const f16* __restrict__ qhl,
                 const f16* __restrict__ khh, const f16* __restrict__ khl,
                 const f16* __restrict__ vht, unsigned short* __restrict__ ao) {
  __shared__ f16 Ksh[2][64 * 64];     // [buf][kv][d], 128B rows, swizzled
  __shared__ f16 Ksl[2][64 * 64];
  __shared__ f16 Vts[2][64 * 64];     // [buf][d][kv], 128B rows, swizzled
  __shared__ f16 Pls[4][32 * 64];     // per-wave [q][kv], swizzled
  const int t = threadIdx.x;
  const int b = blockIdx.z, h = blockIdx.y;
  const int w = t >> 6, l = t & 63, lr = l & 15, lg = l >> 4;
  const size_t bh = ((size_t)b * H_ + h) * S_;
  const size_t bhD = ((size_t)b * H_ + h) * D_;
  // Staging chunk mapping (512 chunks = 64 rows x 8 chunks of 8 f16).
  const int cr0 = t >> 3, cch = t & 7;          // j=0 chunk
  const int cr1 = (t + 256) >> 3;               // j=1 chunk (same cch)
  const int coff = (cch * 16);

#pragma unroll
  for (int ph = 0; ph < 2; ++ph) {
    const int qt = ph ? (15 - (int)blockIdx.x) : (int)blockIdx.x;
    const int q0 = qt * 128;

    // Q fragments in registers (hi/lo), rows w*32 + i*16 + lr.
    f16x8 qfh[2][2], qfl[2][2];
#pragma unroll
    for (int i = 0; i < 2; ++i) {
      const size_t qo = (bh + q0 + w * 32 + i * 16 + lr) * D_;
#pragma unroll
      for (int hf = 0; hf < 2; ++hf) {
        qfh[i][hf] = *(const f16x8*)(qhh + qo + hf * 32 + lg * 8);
        qfl[i][hf] = *(const f16x8*)(qhl + qo + hf * 32 + lg * 8);
      }
    }

    f32x4 acc[2][4];
#pragma unroll
    for (int i = 0; i < 2; ++i)
#pragma unroll
      for (int c = 0; c < 4; ++c) acc[i][c] = (f32x4){0.f, 0.f, 0.f, 0.f};
    float mx[2][4], ls[2][4];
#pragma unroll
    for (int i = 0; i < 2; ++i)
#pragma unroll
      for (int r = 0; r < 4; ++r) { mx[i][r] = -3.0e38f; ls[i][r] = 0.f; }

    const int wmax = q0 + w * 32 + 31;  // last q-row this wave owns
    const int nkt = 2 * qt + 2;
    int cur = 0;

    // Prologue: stage tile 0 into buffer 0.
    {
      const f16* kbh = khh + bh * D_;
      const f16* kbl = khl + bh * D_;
      const f16* vb = vht + bhD * S_;
      f16x8 a0 = *(const f16x8*)(kbh + cr0 * 64 + cch * 8);
      f16x8 a1 = *(const f16x8*)(kbh + cr1 * 64 + cch * 8);
      f16x8 b0 = *(const f16x8*)(kbl + cr0 * 64 + cch * 8);
      f16x8 b1 = *(const f16x8*)(kbl + cr1 * 64 + cch * 8);
      f16x8 c0 = *(const f16x8*)(vb + (size_t)cr0 * S_ + cch * 8);
      f16x8 c1 = *(const f16x8*)(vb + (size_t)cr1 * S_ + cch * 8);
      const int o0 = coff ^ ((cr0 & 7) << 4);
      const int o1 = coff ^ ((cr1 & 7) << 4);
      *(f16x8*)((char*)Ksh[0] + cr0 * 128 + o0) = a0;
      *(f16x8*)((char*)Ksh[0] + cr1 * 128 + o1) = a1;
      *(f16x8*)((char*)Ksl[0] + cr0 * 128 + o0) = b0;
      *(f16x8*)((char*)Ksl[0] + cr1 * 128 + o1) = b1;
      *(f16x8*)((char*)Vts[0] + cr0 * 128 + o0) = c0;
      *(f16x8*)((char*)Vts[0] + cr1 * 128 + o1) = c1;
    }

    for (int kt = 0; kt < nkt; ++kt) {
      const int kt0 = kt * 64;
      __syncthreads();  // A: lds[cur] published

      // Prefetch next tile into registers (stays in flight over compute).
      const bool pf = (kt + 1 < nkt);
      f16x8 ra0, ra1, rb0, rb1, rc0, rc1;
      if (pf) {
        const int n0 = kt0 + 64;
        const f16* kbh = khh + (bh + n0) * D_;
        const f16* kbl = khl + (bh + n0) * D_;
        const f16* vb = vht + bhD * S_ + n0;
        ra0 = *(const f16x8*)(kbh + cr0 * 64 + cch * 8);
        ra1 = *(const f16x8*)(kbh + cr1 * 64 + cch * 8);
        rb0 = *(const f16x8*)(kbl + cr0 * 64 + cch * 8);
        rb1 = *(const f16x8*)(kbl + cr1 * 64 + cch * 8);
        rc0 = *(const f16x8*)(vb + (size_t)cr0 * S_ + cch * 8);
        rc1 = *(const f16x8*)(vb + (size_t)cr1 * S_ + cch * 8);
      }

      if (kt0 <= wmax) {  // wave-uniform causal skip
        // QK^T: 48 MFMA per wave (2 i-groups x 4 n-tiles x 6 split-terms).
        f32x4 sc[2][4];
#pragma unroll
        for (int n = 0; n < 4; ++n) {
          const int krow = n * 16 + lr;
          const int sw = (krow & 7) << 4;
          const char* kb = (const char*)Ksh[cur] + krow * 128;
          const char* kbl2 = (const char*)Ksl[cur] + krow * 128;
          f16x8 kh0 = *(const f16x8*)(kb + ((lg * 16) ^ sw));
          f16x8 kh1 = *(const f16x8*)(kb + ((64 + lg * 16) ^ sw));
          f16x8 kl0 = *(const f16x8*)(kbl2 + ((lg * 16) ^ sw));
          f16x8 kl1 = *(const f16x8*)(kbl2 + ((64 + lg * 16) ^ sw));
#pragma unroll
          for (int i = 0; i < 2; ++i) {
            f32x4 z = (f32x4){0.f, 0.f, 0.f, 0.f};
            z = MFMA_F16(qfh[i][0], kh0, z);
            z = MFMA_F16(qfh[i][1], kh1, z);
            z = MFMA_F16(qfh[i][0], kl0, z);
            z = MFMA_F16(qfh[i][1], kl1, z);
            z = MFMA_F16(qfl[i][0], kh0, z);
            z = MFMA_F16(qfl[i][1], kh1, z);
            sc[i][n] = z;
          }
        }

        // Online softmax per i-group; write P (f16) to per-wave swizzled LDS.
#pragma unroll
        for (int i = 0; i < 2; ++i) {
          const int qbase = q0 + w * 32 + i * 16;
          const bool full = (kt0 + 63 <= qbase);
#pragma unroll
          for (int r = 0; r < 4; ++r) {
            const int qrow = qbase + lg * 4 + r;
            float v0 = sc[i][0][r], v1 = sc[i][1][r], v2 = sc[i][2][r], v3 = sc[i][3][r];
            if (!full) {
              v0 = (kt0 + 0 + lr <= qrow) ? v0 : -3.0e38f;
              v1 = (kt0 + 16 + lr <= qrow) ? v1 : -3.0e38f;
              v2 = (kt0 + 32 + lr <= qrow) ? v2 : -3.0e38f;
              v3 = (kt0 + 48 + lr <= qrow) ? v3 : -3.0e38f;
            }
            float tm = fmaxf(fmaxf(v0, v1), fmaxf(v2, v3));
            tm = fmaxf(tm, __shfl_xor(tm, 1));
            tm = fmaxf(tm, __shfl_xor(tm, 2));
            tm = fmaxf(tm, __shfl_xor(tm, 4));
            tm = fmaxf(tm, __shfl_xor(tm, 8));
            const float mn = fmaxf(mx[i][r], tm);
            const float corr = __expf(mx[i][r] - mn);
            mx[i][r] = mn;
            float p0 = __expf(v0 - mn), p1 = __expf(v1 - mn);
            float p2 = __expf(v2 - mn), p3 = __expf(v3 - mn);
            float ps = (p0 + p1) + (p2 + p3);
            ps += __shfl_xor(ps, 1);
            ps += __shfl_xor(ps, 2);
            ps += __shfl_xor(ps, 4);
            ps += __shfl_xor(ps, 8);
            ls[i][r] = ls[i][r] * corr + ps;
#pragma unroll
            for (int c = 0; c < 4; ++c) acc[i][c][r] *= corr;
            const int qi = i * 16 + lg * 4 + r;
            char* pb = (char*)&Pls[w][0] + qi * 128;
            const int sw2 = (qi & 7) << 4;
            *(f16*)(pb + ((0 + lr * 2) ^ sw2)) = (f16)p0;
            *(f16*)(pb + ((32 + lr * 2) ^ sw2)) = (f16)p1;
            *(f16*)(pb + ((64 + lr * 2) ^ sw2)) = (f16)p2;
            *(f16*)(pb + ((96 + lr * 2) ^ sw2)) = (f16)p3;
          }
        }

        // PV: 16 MFMA per wave. P is per-wave (no barrier needed).
#pragma unroll
        for (int ks = 0; ks < 2; ++ks) {
          const int co = (ks * 64 + lg * 16);
          f16x8 pf0 = *(const f16x8*)((const char*)&Pls[w][0] + lr * 128 + (co ^ ((lr & 7) << 4)));
          f16x8 pf1 = *(const f16x8*)((const char*)&Pls[w][0] + (16 + lr) * 128 + (co ^ ((lr & 7) << 4)));
#pragma unroll
          for (int c = 0; c < 4; ++c) {
            const int vr = c * 16 + lr;
            f16x8 vf = *(const f16x8*)((const char*)Vts[cur] + vr * 128 + (co ^ ((vr & 7) << 4)));
            acc[0][c] = MFMA_F16(pf0, vf, acc[0][c]);
            acc[1][c] = MFMA_F16(pf1, vf, acc[1][c]);
          }
        }
      }

      __syncthreads();  // B: all readers done with lds[cur]
      if (pf) {
        const int nb = cur ^ 1;
        const int o0 = coff ^ ((cr0 & 7) << 4);
        const int o1 = coff ^ ((cr1 & 7) << 4);
        *(f16x8*)((char*)Ksh[nb] + cr0 * 128 + o0) = ra0;
        *(f16x8*)((char*)Ksh[nb] + cr1 * 128 + o1) = ra1;
        *(f16x8*)((char*)Ksl[nb] + cr0 * 128 + o0) = rb0;
        *(f16x8*)((char*)Ksl[nb] + cr1 * 128 + o1) = rb1;
        *(f16x8*)((char*)Vts[nb] + cr0 * 128 + o0) = rc0;
        *(f16x8*)((char*)Vts[nb] + cr1 * 128 + o1) = rc1;
      }
      cur ^= 1;
    }

    // Epilogue: ao[b][s][h][d] bf16 for this q-tile.
#pragma unroll
    for (int i = 0; i < 2; ++i)
#pragma unroll
      for (int r = 0; r < 4; ++r) {
        const float inv = 1.0f / ls[i][r];
        const size_t s = q0 + w * 32 + i * 16 + lg * 4 + r;
        const size_t o = ((size_t)b * S_ + s) * (H_ * D_) + (size_t)h * D_;
#pragma unroll
        for (int c = 0; c < 4; ++c)
          ao[o + c * 16 + lr] = f2bf(acc[i][c][r] * inv);
      }
  }
}

// Output projection: d_out[m][n] = sum_k ao[m][k] * Wo[k][n] (Wot = Wo^T bf16)
__global__ __launch_bounds__(256)
void out_gemm(const unsigned short* __restrict__ A, const unsigned short* __restrict__ Bt,
              float* __restrict__ Cout) {
  __shared__ unsigned short As[128 * 32];
  __shared__ unsigned short Bs[64 * 32];
  const int t = threadIdx.x;
  const int m0 = blockIdx.x * 128;
  const int n0 = blockIdx.y * 64;
  const int arow = t >> 1, ac0 = (t & 1) * 16;
  const unsigned short* aptr = A + (size_t)(m0 + arow) * 1024 + ac0;
  const int brow = t >> 2, bc0 = (t & 3) * 8;
  const unsigned short* bptr = Bt + (size_t)(n0 + brow) * 1024 + bc0;
  const int w = t >> 6, l = t & 63, lr = l & 15, lg = l >> 4;

  f32x4 acc[2][4];
#pragma unroll
  for (int i = 0; i < 2; ++i)
#pragma unroll
    for (int c = 0; c < 4; ++c) acc[i][c] = (f32x4){0.f, 0.f, 0.f, 0.f};

  for (int k0 = 0; k0 < 1024; k0 += 32) {
    __syncthreads();
    *(u16x8*)&As[arow * 32 + ac0] = *(const u16x8*)(aptr + k0);
    *(u16x8*)&As[arow * 32 + ac0 + 8] = *(const u16x8*)(aptr + k0 + 8);
    *(u16x8*)&Bs[brow * 32 + bc0] = *(const u16x8*)(bptr + k0);
    __syncthreads();

    bf16x8 af0 = *(const bf16x8*)&As[(w * 32 + lr) * 32 + lg * 8];
    bf16x8 af1 = *(const bf16x8*)&As[(w * 32 + 16 + lr) * 32 + lg * 8];
#pragma unroll
    for (int c = 0; c < 4; ++c) {
      bf16x8 bf = *(const bf16x8*)&Bs[(c * 16 + lr) * 32 + lg * 8];
      acc[0][c] = MFMA_BF(af0, bf, acc[0][c]);
      acc[1][c] = MFMA_BF(af1, bf, acc[1][c]);
    }
  }

#pragma unroll
  for (int i = 0; i < 2; ++i)
#pragma unroll
    for (int c = 0; c < 4; ++c)
#pragma unroll
      for (int r = 0; r < 4; ++r) {
        const int row = m0 + w * 32 + i * 16 + lg * 4 + r;
        const int col = n0 + c * 16 + lr;
        Cout[(size_t)row * 1024 + col] = acc[i][c][r];
      }
}

extern "C" void kernel_launch(void* const* d_in, const int* in_sizes, int n_in,
                              void* d_out, int out_size, void* d_ws, size_t ws_size,
                              hipStream_t stream) {
  const float* q = (const float*)d_in[0];
  const float* k = (const float*)d_in[1];
  const float* v = (const float*)d_in[2];
  const float* Wq = (const float*)d_in[3];
  const float* Wk = (const float*)d_in[4];
  const float* Wv = (const float*)d_in[5];
  const float* Wo = (const float*)d_in[6];

  const size_t NBH = (size_t)B_ * H_ * S_ * D_;   // 8388608
  const size_t WSZ = (size_t)H_ * D_ * E_;        // 1048576

  char* wsb = (char*)d_ws;
  f16* qk_hi = (f16*)wsb;                          // [2][B][H][S][D]
  f16* qk_lo = qk_hi + 2 * NBH;                    // [2][B][H][S][D]
  f16* vht = qk_lo + 2 * NBH;                      // [B][H][D][S] (transposed)
  unsigned short* ao = (unsigned short*)(vht + NBH); // [B][S][H][D]
  f16* Wqk_hi = (f16*)(ao + NBH);                  // [2][H][D][E]
  f16* Wqk_lo = Wqk_hi + 2 * WSZ;
  unsigned short* Wvt = (unsigned short*)(Wqk_lo + 2 * WSZ); // [H][D][E]
  unsigned short* Wot = Wvt + WSZ;                 // [E][H*D]

  dim3 blk(256);
  // Weight prep (x8 quirk folded into Wq, exact).
  transpose_split_f16<<<dim3(1, 16, 16), blk, 0, stream>>>(Wq, Wqk_hi, Wqk_lo, E_, D_, 8.0f);
  transpose_split_f16<<<dim3(1, 16, 16), blk, 0, stream>>>(Wk, Wqk_hi + WSZ, Wqk_lo + WSZ, E_, D_, 1.0f);
  transpose_convert<<<dim3(1, 16, 16), blk, 0, stream>>>(Wv, Wvt, E_, D_, 1.0f);
  transpose_convert<<<dim3(16, 16, 1), blk, 0, stream>>>(Wo, Wot, E_, E_, 1.0f);
  // Projections.
  proj_qk<<<dim3(S_ / 128, H_, 8), blk, 0, stream>>>(q, k, Wqk_hi, Wqk_lo, qk_hi, qk_lo);
  proj_v<<<dim3(S_ / 128, H_, B_), blk, 0, stream>>>(v, Wvt, vht);
  // Attention (paired q-tiles: block x handles q-tiles x and 15-x).
  attn_kernel<<<dim3(S_ / 256, H_, B_), blk, 0, stream>>>(
      qk_hi, qk_lo, qk_hi + NBH, qk_lo + NBH, vht, ao);
  // Output projection.
  out_gemm<<<dim3((B_ * S_) / 128, E_ / 64), blk, 0, stream>>>(ao, Wot, (float*)d_out);
}

// Round 7
// 498.713 us; speedup vs baseline: 1.7614x; 1.0337x over previous
//
#include <hip/hip_runtime.h>
#include <hip/hip_bf16.h>

#define B_ 4
#define S_ 2048
#define E_ 1024
#define H_ 16
#define D_ 64
#define LDW 40  // padded LDS row stride (f16/u16) for 32-wide K tiles (80 B)

typedef _Float16 f16;
typedef __attribute__((ext_vector_type(4))) float f32x4;
typedef __attribute__((ext_vector_type(8))) short bf16x8;
typedef __attribute__((ext_vector_type(8))) unsigned short u16x8;
typedef __attribute__((ext_vector_type(8))) _Float16 f16x8;
typedef __attribute__((ext_vector_type(4))) float float4v;

__device__ __forceinline__ unsigned short f2bf(float f) {
  union { float f; unsigned int u; } x; x.f = f;
  unsigned int u = x.u;
  u = (u + 0x7FFFu + ((u >> 16) & 1u)) >> 16;
  return (unsigned short)u;
}

#define MFMA_BF(a, b, c) __builtin_amdgcn_mfma_f32_16x16x32_bf16((a), (b), (c), 0, 0, 0)
#define MFMA_F16(a, b, c) __builtin_amdgcn_mfma_f32_16x16x32_f16((a), (b), (c), 0, 0, 0)

// fp32 [z][R][C] -> bf16 [z][C][R]
__global__ __launch_bounds__(256)
void transpose_convert(const float* __restrict__ src, unsigned short* __restrict__ dst,
                       int R, int C, float scale) {
  __shared__ unsigned short tile[64][65];
  const int rb = blockIdx.y * 64;
  const int cb = blockIdx.x * 64;
  const size_t mo = (size_t)blockIdx.z * (size_t)R * (size_t)C;
  const int t = threadIdx.x;
  const int r = t >> 2;
  const int c0 = (t & 3) * 16;
  const float* sp = src + mo + (size_t)(rb + r) * C + cb + c0;
#pragma unroll
  for (int j = 0; j < 16; j += 4) {
    float4v vv = *(const float4v*)(sp + j);
    tile[r][c0 + j + 0] = f2bf(vv[0] * scale);
    tile[r][c0 + j + 1] = f2bf(vv[1] * scale);
    tile[r][c0 + j + 2] = f2bf(vv[2] * scale);
    tile[r][c0 + j + 3] = f2bf(vv[3] * scale);
  }
  __syncthreads();
  u16x8 w0, w1;
#pragma unroll
  for (int j = 0; j < 8; ++j) w0[j] = tile[c0 + j][r];
#pragma unroll
  for (int j = 0; j < 8; ++j) w1[j] = tile[c0 + 8 + j][r];
  unsigned short* dp = dst + mo + (size_t)(cb + r) * R + rb + c0;
  *(u16x8*)(dp) = w0;
  *(u16x8*)(dp + 8) = w1;
}

// fp32 [z][R][C] -> f16 hi/lo [z][C][R] (2-way split, ~23-bit effective)
__global__ __launch_bounds__(256)
void transpose_split_f16(const float* __restrict__ src, f16* __restrict__ dhi,
                         f16* __restrict__ dlo, int R, int C, float scale) {
  __shared__ float tile[64][65];
  const int rb = blockIdx.y * 64;
  const int cb = blockIdx.x * 64;
  const size_t mo = (size_t)blockIdx.z * (size_t)R * (size_t)C;
  const int t = threadIdx.x;
  const int r = t >> 2;
  const int c0 = (t & 3) * 16;
  const float* sp = src + mo + (size_t)(rb + r) * C + cb + c0;
#pragma unroll
  for (int j = 0; j < 16; j += 4) {
    float4v vv = *(const float4v*)(sp + j);
    tile[r][c0 + j + 0] = vv[0] * scale;
    tile[r][c0 + j + 1] = vv[1] * scale;
    tile[r][c0 + j + 2] = vv[2] * scale;
    tile[r][c0 + j + 3] = vv[3] * scale;
  }
  __syncthreads();
  f16x8 h0, h1, l0, l1;
#pragma unroll
  for (int j = 0; j < 8; ++j) {
    float x = tile[c0 + j][r];
    f16 hi = (f16)x;
    h0[j] = hi; l0[j] = (f16)(x - (float)hi);
  }
#pragma unroll
  for (int j = 0; j < 8; ++j) {
    float x = tile[c0 + 8 + j][r];
    f16 hi = (f16)x;
    h1[j] = hi; l1[j] = (f16)(x - (float)hi);
  }
  const size_t o = mo + (size_t)(cb + r) * R + rb + c0;
  *(f16x8*)(dhi + o) = h0; *(f16x8*)(dhi + o + 8) = h1;
  *(f16x8*)(dlo + o) = l0; *(f16x8*)(dlo + o + 8) = l1;
}

// fp32 -> f16 hi/lo, flat; 8 elems/thread
__global__ __launch_bounds__(256)
void prep_split(const float* __restrict__ x, f16* __restrict__ xh, f16* __restrict__ xl) {
  const size_t i = ((size_t)blockIdx.x * 256 + threadIdx.x) * 8;
  float4v a = *(const float4v*)(x + i);
  float4v b = *(const float4v*)(x + i + 4);
  f16x8 h, lo;
#pragma unroll
  for (int j = 0; j < 4; ++j) {
    f16 hi = (f16)a[j]; h[j] = hi; lo[j] = (f16)(a[j] - (float)hi);
  }
#pragma unroll
  for (int j = 0; j < 4; ++j) {
    f16 hi = (f16)b[j]; h[4 + j] = hi; lo[4 + j] = (f16)(b[j] - (float)hi);
  }
  *(f16x8*)(xh + i) = h;
  *(f16x8*)(xl + i) = lo;
}

// fp32 -> bf16, flat; 8 elems/thread
__global__ __launch_bounds__(256)
void prep_bf16(const float* __restrict__ x, unsigned short* __restrict__ xo) {
  const size_t i = ((size_t)blockIdx.x * 256 + threadIdx.x) * 8;
  float4v a = *(const float4v*)(x + i);
  float4v b = *(const float4v*)(x + i + 4);
  u16x8 o;
#pragma unroll
  for (int j = 0; j < 4; ++j) { o[j] = f2bf(a[j]); o[4 + j] = f2bf(b[j]); }
  *(u16x8*)(xo + i) = o;
}

// Q/K projection v2: wide GEMM [8192 x 1024] @ [1024 n x 1024 k]^T-form,
// 3-term split-f16, 128x128 tile, BK=32, reg-prefetch double buffer.
// out: [b][h][s][d] f16 hi/lo (n = h*64+d).
__global__ __launch_bounds__(256, 2)
void proj_qk2(const f16* __restrict__ xh, const f16* __restrict__ xl,
              const f16* __restrict__ Wh, const f16* __restrict__ Wl,
              f16* __restrict__ out_hi, f16* __restrict__ out_lo) {
  __shared__ f16 Ah[128 * LDW], Al[128 * LDW], Bh[128 * LDW], Bl[128 * LDW];
  const int t = threadIdx.x;
  const int m0 = blockIdx.x * 128, n0 = blockIdx.y * 128;
  const int w = t >> 6, l = t & 63, lr = l & 15, lg = l >> 4;
  const int wm = (w & 1) * 64, wn = (w >> 1) * 64;

  const int sr0 = t >> 2, sc = (t & 3) * 8;
  const f16* gAh = xh + (size_t)(m0 + sr0) * 1024 + sc;
  const f16* gAl = xl + (size_t)(m0 + sr0) * 1024 + sc;
  const f16* gBh = Wh + (size_t)(n0 + sr0) * 1024 + sc;
  const f16* gBl = Wl + (size_t)(n0 + sr0) * 1024 + sc;
  const size_t rstep = (size_t)64 * 1024;
  const int l0 = sr0 * LDW + sc, l1 = (sr0 + 64) * LDW + sc;

  f32x4 acc[4][4];
#pragma unroll
  for (int im = 0; im < 4; ++im)
#pragma unroll
    for (int in = 0; in < 4; ++in) acc[im][in] = (f32x4){0.f, 0.f, 0.f, 0.f};

  // prologue: stage k0 = 0
  f16x8 r0 = *(const f16x8*)(gAh),         r1 = *(const f16x8*)(gAh + rstep);
  f16x8 r2 = *(const f16x8*)(gAl),         r3 = *(const f16x8*)(gAl + rstep);
  f16x8 r4 = *(const f16x8*)(gBh),         r5 = *(const f16x8*)(gBh + rstep);
  f16x8 r6 = *(const f16x8*)(gBl),         r7 = *(const f16x8*)(gBl + rstep);
  *(f16x8*)&Ah[l0] = r0; *(f16x8*)&Ah[l1] = r1;
  *(f16x8*)&Al[l0] = r2; *(f16x8*)&Al[l1] = r3;
  *(f16x8*)&Bh[l0] = r4; *(f16x8*)&Bh[l1] = r5;
  *(f16x8*)&Bl[l0] = r6; *(f16x8*)&Bl[l1] = r7;

  for (int k0 = 0; k0 < 1024; k0 += 32) {
    __syncthreads();  // LDS[k0] published
    const bool pf = (k0 + 32 < 1024);
    if (pf) {
      r0 = *(const f16x8*)(gAh + k0 + 32); r1 = *(const f16x8*)(gAh + rstep + k0 + 32);
      r2 = *(const f16x8*)(gAl + k0 + 32); r3 = *(const f16x8*)(gAl + rstep + k0 + 32);
      r4 = *(const f16x8*)(gBh + k0 + 32); r5 = *(const f16x8*)(gBh + rstep + k0 + 32);
      r6 = *(const f16x8*)(gBl + k0 + 32); r7 = *(const f16x8*)(gBl + rstep + k0 + 32);
    }
    f16x8 afh[4], afl[4], bfh[4], bfl[4];
#pragma unroll
    for (int im = 0; im < 4; ++im) {
      afh[im] = *(const f16x8*)&Ah[(wm + im * 16 + lr) * LDW + lg * 8];
      afl[im] = *(const f16x8*)&Al[(wm + im * 16 + lr) * LDW + lg * 8];
    }
#pragma unroll
    for (int in = 0; in < 4; ++in) {
      bfh[in] = *(const f16x8*)&Bh[(wn + in * 16 + lr) * LDW + lg * 8];
      bfl[in] = *(const f16x8*)&Bl[(wn + in * 16 + lr) * LDW + lg * 8];
    }
#pragma unroll
    for (int im = 0; im < 4; ++im)
#pragma unroll
      for (int in = 0; in < 4; ++in) {
        acc[im][in] = MFMA_F16(afh[im], bfh[in], acc[im][in]);
        acc[im][in] = MFMA_F16(afh[im], bfl[in], acc[im][in]);
        acc[im][in] = MFMA_F16(afl[im], bfh[in], acc[im][in]);
      }
    __syncthreads();  // readers done
    if (pf) {
      *(f16x8*)&Ah[l0] = r0; *(f16x8*)&Ah[l1] = r1;
      *(f16x8*)&Al[l0] = r2; *(f16x8*)&Al[l1] = r3;
      *(f16x8*)&Bh[l0] = r4; *(f16x8*)&Bh[l1] = r5;
      *(f16x8*)&Bl[l0] = r6; *(f16x8*)&Bl[l1] = r7;
    }
  }

  const int b = m0 >> 11, s0b = m0 & 2047;
#pragma unroll
  for (int im = 0; im < 4; ++im)
#pragma unroll
    for (int in = 0; in < 4; ++in)
#pragma unroll
      for (int rr = 0; rr < 4; ++rr) {
        const int srow = s0b + wm + im * 16 + lg * 4 + rr;
        const int n = n0 + wn + in * 16 + lr;
        const int h = n >> 6, d = n & 63;
        const size_t o = (((size_t)b * H_ + h) * S_ + srow) * D_ + d;
        const float x = acc[im][in][rr];
        const f16 hi = (f16)x;
        out_hi[o] = hi;
        out_lo[o] = (f16)(x - (float)hi);
      }
}

// V projection v2: bf16 GEMM 128x128, BK=32; epilogue transposes to
// vht[b][h][d][s] f16 via LDS.
__global__ __launch_bounds__(256, 2)
void proj_v2(const unsigned short* __restrict__ xv, const unsigned short* __restrict__ Wv,
             f16* __restrict__ vht) {
  __shared__ short smem[17408];  // GEMM: As/Bs (2x5120 u16); epilogue: Td[128][136] f16
  unsigned short* As = (unsigned short*)smem;
  unsigned short* Bs = As + 128 * LDW;
  const int t = threadIdx.x;
  const int m0 = blockIdx.x * 128, n0 = blockIdx.y * 128;
  const int w = t >> 6, l = t & 63, lr = l & 15, lg = l >> 4;
  const int wm = (w & 1) * 64, wn = (w >> 1) * 64;

  const int sr0 = t >> 2, sc = (t & 3) * 8;
  const unsigned short* gA = xv + (size_t)(m0 + sr0) * 1024 + sc;
  const unsigned short* gB = Wv + (size_t)(n0 + sr0) * 1024 + sc;
  const size_t rstep = (size_t)64 * 1024;
  const int l0 = sr0 * LDW + sc, l1 = (sr0 + 64) * LDW + sc;

  f32x4 acc[4][4];
#pragma unroll
  for (int im = 0; im < 4; ++im)
#pragma unroll
    for (int in = 0; in < 4; ++in) acc[im][in] = (f32x4){0.f, 0.f, 0.f, 0.f};

  u16x8 r0 = *(const u16x8*)(gA), r1 = *(const u16x8*)(gA + rstep);
  u16x8 r2 = *(const u16x8*)(gB), r3 = *(const u16x8*)(gB + rstep);
  *(u16x8*)&As[l0] = r0; *(u16x8*)&As[l1] = r1;
  *(u16x8*)&Bs[l0] = r2; *(u16x8*)&Bs[l1] = r3;

  for (int k0 = 0; k0 < 1024; k0 += 32) {
    __syncthreads();
    const bool pf = (k0 + 32 < 1024);
    if (pf) {
      r0 = *(const u16x8*)(gA + k0 + 32); r1 = *(const u16x8*)(gA + rstep + k0 + 32);
      r2 = *(const u16x8*)(gB + k0 + 32); r3 = *(const u16x8*)(gB + rstep + k0 + 32);
    }
    bf16x8 af[4], bf[4];
#pragma unroll
    for (int im = 0; im < 4; ++im)
      af[im] = *(const bf16x8*)&As[(wm + im * 16 + lr) * LDW + lg * 8];
#pragma unroll
    for (int in = 0; in < 4; ++in)
      bf[in] = *(const bf16x8*)&Bs[(wn + in * 16 + lr) * LDW + lg * 8];
#pragma unroll
    for (int im = 0; im < 4; ++im)
#pragma unroll
      for (int in = 0; in < 4; ++in)
        acc[im][in] = MFMA_BF(af[im], bf[in], acc[im][in]);
    __syncthreads();
    if (pf) {
      *(u16x8*)&As[l0] = r0; *(u16x8*)&As[l1] = r1;
      *(u16x8*)&Bs[l0] = r2; *(u16x8*)&Bs[l1] = r3;
    }
  }

  // Transpose epilogue: Td[n][s] (stride 136), then coalesced f16 writes.
  __syncthreads();
  f16* Td = (f16*)smem;
#pragma unroll
  for (int im = 0; im < 4; ++im)
#pragma unroll
    for (int in = 0; in < 4; ++in)
#pragma unroll
      for (int rr = 0; rr < 4; ++rr) {
        const int srow = wm + im * 16 + lg * 4 + rr;   // 0..127
        const int ncol = wn + in * 16 + lr;            // 0..127
        Td[ncol * 136 + srow] = (f16)acc[im][in][rr];
      }
  __syncthreads();
  const int n = t >> 1, sc2 = (t & 1) * 64;
  const int b = m0 >> 11, s0b = m0 & 2047;
  const int h = (n0 + n) >> 6, d = (n0 + n) & 63;
  f16* vp = vht + (((size_t)b * H_ + h) * D_ + d) * S_ + s0b + sc2;
#pragma unroll
  for (int j = 0; j < 8; ++j)
    *(f16x8*)(vp + j * 8) = *(const f16x8*)&Td[n * 136 + sc2 + j * 8];
}

// Output projection v2: bf16 GEMM 128x128, BK=32, fp32 output.
__global__ __launch_bounds__(256, 2)
void out_gemm2(const unsigned short* __restrict__ A, const unsigned short* __restrict__ Bt,
               float* __restrict__ Cout) {
  __shared__ unsigned short As[128 * LDW], Bs[128 * LDW];
  const int t = threadIdx.x;
  const int m0 = blockIdx.x * 128, n0 = blockIdx.y * 128;
  const int w = t >> 6, l = t & 63, lr = l & 15, lg = l >> 4;
  const int wm = (w & 1) * 64, wn = (w >> 1) * 64;

  const int sr0 = t >> 2, sc = (t & 3) * 8;
  const unsigned short* gA = A + (size_t)(m0 + sr0) * 1024 + sc;
  const unsigned short* gB = Bt + (size_t)(n0 + sr0) * 1024 + sc;
  const size_t rstep = (size_t)64 * 1024;
  const int l0 = sr0 * LDW + sc, l1 = (sr0 + 64) * LDW + sc;

  f32x4 acc[4][4];
#pragma unroll
  for (int im = 0; im < 4; ++im)
#pragma unroll
    for (int in = 0; in < 4; ++in) acc[im][in] = (f32x4){0.f, 0.f, 0.f, 0.f};

  u16x8 r0 = *(const u16x8*)(gA), r1 = *(const u16x8*)(gA + rstep);
  u16x8 r2 = *(const u16x8*)(gB), r3 = *(const u16x8*)(gB + rstep);
  *(u16x8*)&As[l0] = r0; *(u16x8*)&As[l1] = r1;
  *(u16x8*)&Bs[l0] = r2; *(u16x8*)&Bs[l1] = r3;

  for (int k0 = 0; k0 < 1024; k0 += 32) {
    __syncthreads();
    const bool pf = (k0 + 32 < 1024);
    if (pf) {
      r0 = *(const u16x8*)(gA + k0 + 32); r1 = *(const u16x8*)(gA + rstep + k0 + 32);
      r2 = *(const u16x8*)(gB + k0 + 32); r3 = *(const u16x8*)(gB + rstep + k0 + 32);
    }
    bf16x8 af[4], bf[4];
#pragma unroll
    for (int im = 0; im < 4; ++im)
      af[im] = *(const bf16x8*)&As[(wm + im * 16 + lr) * LDW + lg * 8];
#pragma unroll
    for (int in = 0; in < 4; ++in)
      bf[in] = *(const bf16x8*)&Bs[(wn + in * 16 + lr) * LDW + lg * 8];
#pragma unroll
    for (int im = 0; im < 4; ++im)
#pragma unroll
      for (int in = 0; in < 4; ++in)
        acc[im][in] = MFMA_BF(af[im], bf[in], acc[im][in]);
    __syncthreads();
    if (pf) {
      *(u16x8*)&As[l0] = r0; *(u16x8*)&As[l1] = r1;
      *(u16x8*)&Bs[l0] = r2; *(u16x8*)&Bs[l1] = r3;
    }
  }

#pragma unroll
  for (int im = 0; im < 4; ++im)
#pragma unroll
    for (int in = 0; in < 4; ++in)
#pragma unroll
      for (int rr = 0; rr < 4; ++rr) {
        const int row = m0 + wm + im * 16 + lg * 4 + rr;
        const int col = n0 + wn + in * 16 + lr;
        Cout[(size_t)row * 1024 + col] = acc[im][in][rr];
      }
}

// Causal flash attention v3 (unchanged from R6): paired q-tiles (x, 15-x),
// reg-prefetch double-buffered K/V staging, XOR-swizzled LDS.
__global__ __launch_bounds__(256, 2)
void attn_kernel(const f16* __restrict__ qhh, const f16* __restrict__ qhl,
                 const f16* __restrict__ khh, const f16* __restrict__ khl,
                 const f16* __restrict__ vht, unsigned short* __restrict__ ao) {
  __shared__ f16 Ksh[2][64 * 64];
  __shared__ f16 Ksl[2][64 * 64];
  __shared__ f16 Vts[2][64 * 64];
  __shared__ f16 Pls[4][32 * 64];
  const int t = threadIdx.x;
  const int b = blockIdx.z, h = blockIdx.y;
  const int w = t >> 6, l = t & 63, lr = l & 15, lg = l >> 4;
  const size_t bh = ((size_t)b * H_ + h) * S_;
  const size_t bhD = ((size_t)b * H_ + h) * D_;
  const int cr0 = t >> 3, cch = t & 7;
  const int cr1 = (t + 256) >> 3;
  const int coff = (cch * 16);

#pragma unroll
  for (int ph = 0; ph < 2; ++ph) {
    const int qt = ph ? (15 - (int)blockIdx.x) : (int)blockIdx.x;
    const int q0 = qt * 128;

    f16x8 qfh[2][2], qfl[2][2];
#pragma unroll
    for (int i = 0; i < 2; ++i) {
      const size_t qo = (bh + q0 + w * 32 + i * 16 + lr) * D_;
#pragma unroll
      for (int hf = 0; hf < 2; ++hf) {
        qfh[i][hf] = *(const f16x8*)(qhh + qo + hf * 32 + lg * 8);
        qfl[i][hf] = *(const f16x8*)(qhl + qo + hf * 32 + lg * 8);
      }
    }

    f32x4 acc[2][4];
#pragma unroll
    for (int i = 0; i < 2; ++i)
#pragma unroll
      for (int c = 0; c < 4; ++c) acc[i][c] = (f32x4){0.f, 0.f, 0.f, 0.f};
    float mx[2][4], ls[2][4];
#pragma unroll
    for (int i = 0; i < 2; ++i)
#pragma unroll
      for (int r = 0; r < 4; ++r) { mx[i][r] = -3.0e38f; ls[i][r] = 0.f; }

    const int wmax = q0 + w * 32 + 31;
    const int nkt = 2 * qt + 2;
    int cur = 0;

    {
      const f16* kbh = khh + bh * D_;
      const f16* kbl = khl + bh * D_;
      const f16* vb = vht + bhD * S_;
      f16x8 a0 = *(const f16x8*)(kbh + cr0 * 64 + cch * 8);
      f16x8 a1 = *(const f16x8*)(kbh + cr1 * 64 + cch * 8);
      f16x8 b0 = *(const f16x8*)(kbl + cr0 * 64 + cch * 8);
      f16x8 b1 = *(const f16x8*)(kbl + cr1 * 64 + cch * 8);
      f16x8 c0 = *(const f16x8*)(vb + (size_t)cr0 * S_ + cch * 8);
      f16x8 c1 = *(const f16x8*)(vb + (size_t)cr1 * S_ + cch * 8);
      const int o0 = coff ^ ((cr0 & 7) << 4);
      const int o1 = coff ^ ((cr1 & 7) << 4);
      *(f16x8*)((char*)Ksh[0] + cr0 * 128 + o0) = a0;
      *(f16x8*)((char*)Ksh[0] + cr1 * 128 + o1) = a1;
      *(f16x8*)((char*)Ksl[0] + cr0 * 128 + o0) = b0;
      *(f16x8*)((char*)Ksl[0] + cr1 * 128 + o1) = b1;
      *(f16x8*)((char*)Vts[0] + cr0 * 128 + o0) = c0;
      *(f16x8*)((char*)Vts[0] + cr1 * 128 + o1) = c1;
    }

    for (int kt = 0; kt < nkt; ++kt) {
      const int kt0 = kt * 64;
      __syncthreads();

      const bool pf = (kt + 1 < nkt);
      f16x8 ra0, ra1, rb0, rb1, rc0, rc1;
      if (pf) {
        const int n0 = kt0 + 64;
        const f16* kbh = khh + (bh + n0) * D_;
        const f16* kbl = khl + (bh + n0) * D_;
        const f16* vb = vht + bhD * S_ + n0;
        ra0 = *(const f16x8*)(kbh + cr0 * 64 + cch * 8);
        ra1 = *(const f16x8*)(kbh + cr1 * 64 + cch * 8);
        rb0 = *(const f16x8*)(kbl + cr0 * 64 + cch * 8);
        rb1 = *(const f16x8*)(kbl + cr1 * 64 + cch * 8);
        rc0 = *(const f16x8*)(vb + (size_t)cr0 * S_ + cch * 8);
        rc1 = *(const f16x8*)(vb + (size_t)cr1 * S_ + cch * 8);
      }

      if (kt0 <= wmax) {
        f32x4 sc[2][4];
#pragma unroll
        for (int n = 0; n < 4; ++n) {
          const int krow = n * 16 + lr;
          const int sw = (krow & 7) << 4;
          const char* kb = (const char*)Ksh[cur] + krow * 128;
          const char* kbl2 = (const char*)Ksl[cur] + krow * 128;
          f16x8 kh0 = *(const f16x8*)(kb + ((lg * 16) ^ sw));
          f16x8 kh1 = *(const f16x8*)(kb + ((64 + lg * 16) ^ sw));
          f16x8 kl0 = *(const f16x8*)(kbl2 + ((lg * 16) ^ sw));
          f16x8 kl1 = *(const f16x8*)(kbl2 + ((64 + lg * 16) ^ sw));
#pragma unroll
          for (int i = 0; i < 2; ++i) {
            f32x4 z = (f32x4){0.f, 0.f, 0.f, 0.f};
            z = MFMA_F16(qfh[i][0], kh0, z);
            z = MFMA_F16(qfh[i][1], kh1, z);
            z = MFMA_F16(qfh[i][0], kl0, z);
            z = MFMA_F16(qfh[i][1], kl1, z);
            z = MFMA_F16(qfl[i][0], kh0, z);
            z = MFMA_F16(qfl[i][1], kh1, z);
            sc[i][n] = z;
          }
        }

#pragma unroll
        for (int i = 0; i < 2; ++i) {
          const int qbase = q0 + w * 32 + i * 16;
          const bool full = (kt0 + 63 <= qbase);
#pragma unroll
          for (int r = 0; r < 4; ++r) {
            const int qrow = qbase + lg * 4 + r;
            float v0 = sc[i][0][r], v1 = sc[i][1][r], v2 = sc[i][2][r], v3 = sc[i][3][r];
            if (!full) {
              v0 = (kt0 + 0 + lr <= qrow) ? v0 : -3.0e38f;
              v1 = (kt0 + 16 + lr <= qrow) ? v1 : -3.0e38f;
              v2 = (kt0 + 32 + lr <= qrow) ? v2 : -3.0e38f;
              v3 = (kt0 + 48 + lr <= qrow) ? v3 : -3.0e38f;
            }
            float tm = fmaxf(fmaxf(v0, v1), fmaxf(v2, v3));
            tm = fmaxf(tm, __shfl_xor(tm, 1));
            tm = fmaxf(tm, __shfl_xor(tm, 2));
            tm = fmaxf(tm, __shfl_xor(tm, 4));
            tm = fmaxf(tm, __shfl_xor(tm, 8));
            const float mn = fmaxf(mx[i][r], tm);
            const float corr = __expf(mx[i][r] - mn);
            mx[i][r] = mn;
            float p0 = __expf(v0 - mn), p1 = __expf(v1 - mn);
            float p2 = __expf(v2 - mn), p3 = __expf(v3 - mn);
            float ps = (p0 + p1) + (p2 + p3);
            ps += __shfl_xor(ps, 1);
            ps += __shfl_xor(ps, 2);
            ps += __shfl_xor(ps, 4);
            ps += __shfl_xor(ps, 8);
            ls[i][r] = ls[i][r] * corr + ps;
#pragma unroll
            for (int c = 0; c < 4; ++c) acc[i][c][r] *= corr;
            const int qi = i * 16 + lg * 4 + r;
            char* pb = (char*)&Pls[w][0] + qi * 128;
            const int sw2 = (qi & 7) << 4;
            *(f16*)(pb + ((0 + lr * 2) ^ sw2)) = (f16)p0;
            *(f16*)(pb + ((32 + lr * 2) ^ sw2)) = (f16)p1;
            *(f16*)(pb + ((64 + lr * 2) ^ sw2)) = (f16)p2;
            *(f16*)(pb + ((96 + lr * 2) ^ sw2)) = (f16)p3;
          }
        }

#pragma unroll
        for (int ks = 0; ks < 2; ++ks) {
          const int co = (ks * 64 + lg * 16);
          f16x8 pf0 = *(const f16x8*)((const char*)&Pls[w][0] + lr * 128 + (co ^ ((lr & 7) << 4)));
          f16x8 pf1 = *(const f16x8*)((const char*)&Pls[w][0] + (16 + lr) * 128 + (co ^ ((lr & 7) << 4)));
#pragma unroll
          for (int c = 0; c < 4; ++c) {
            const int vr = c * 16 + lr;
            f16x8 vf = *(const f16x8*)((const char*)Vts[cur] + vr * 128 + (co ^ ((vr & 7) << 4)));
            acc[0][c] = MFMA_F16(pf0, vf, acc[0][c]);
            acc[1][c] = MFMA_F16(pf1, vf, acc[1][c]);
          }
        }
      }

      __syncthreads();
      if (pf) {
        const int nb = cur ^ 1;
        const int o0 = coff ^ ((cr0 & 7) << 4);
        const int o1 = coff ^ ((cr1 & 7) << 4);
        *(f16x8*)((char*)Ksh[nb] + cr0 * 128 + o0) = ra0;
        *(f16x8*)((char*)Ksh[nb] + cr1 * 128 + o1) = ra1;
        *(f16x8*)((char*)Ksl[nb] + cr0 * 128 + o0) = rb0;
        *(f16x8*)((char*)Ksl[nb] + cr1 * 128 + o1) = rb1;
        *(f16x8*)((char*)Vts[nb] + cr0 * 128 + o0) = rc0;
        *(f16x8*)((char*)Vts[nb] + cr1 * 128 + o1) = rc1;
      }
      cur ^= 1;
    }

#pragma unroll
    for (int i = 0; i < 2; ++i)
#pragma unroll
      for (int r = 0; r < 4; ++r) {
        const float inv = 1.0f / ls[i][r];
        const size_t s = q0 + w * 32 + i * 16 + lg * 4 + r;
        const size_t o = ((size_t)b * S_ + s) * (H_ * D_) + (size_t)h * D_;
#pragma unroll
        for (int c = 0; c < 4; ++c)
          ao[o + c * 16 + lr] = f2bf(acc[i][c][r] * inv);
      }
  }
}

extern "C" void kernel_launch(void* const* d_in, const int* in_sizes, int n_in,
                              void* d_out, int out_size, void* d_ws, size_t ws_size,
                              hipStream_t stream) {
  const float* q = (const float*)d_in[0];
  const float* k = (const float*)d_in[1];
  const float* v = (const float*)d_in[2];
  const float* Wq = (const float*)d_in[3];
  const float* Wk = (const float*)d_in[4];
  const float* Wv = (const float*)d_in[5];
  const float* Wo = (const float*)d_in[6];

  const size_t NBH = (size_t)B_ * H_ * S_ * D_;   // 8388608
  const size_t WSZ = (size_t)H_ * D_ * E_;        // 1048576

  // ws layout (108 MB peak, same footprint as the passing R6 kernel):
  // [0,12M): weights; [12M,76M): qk_hi/lo; [76M,108M): flex (xh/xl -> xv/vht -> ao)
  char* wsb = (char*)d_ws;
  f16* Wqk_hi = (f16*)wsb;                               // 2*WSZ f16 (4 MB)
  f16* Wqk_lo = Wqk_hi + 2 * WSZ;                        // 4 MB
  unsigned short* Wvt = (unsigned short*)(Wqk_lo + 2 * WSZ);  // 2 MB
  unsigned short* Wot = Wvt + WSZ;                       // 2 MB
  f16* qk_hi = (f16*)(wsb + (size_t)12 * 1024 * 1024);   // 32 MB
  f16* qk_lo = qk_hi + 2 * NBH;                          // 32 MB
  char* flex = wsb + (size_t)76 * 1024 * 1024;
  f16* xh = (f16*)flex;                                  // 16 MB (phase A)
  f16* xl = (f16*)(flex + (size_t)16 * 1024 * 1024);     // 16 MB (phase A)
  unsigned short* xv = (unsigned short*)flex;            // 16 MB (phase B, over xh)
  f16* vht = (f16*)(flex + (size_t)16 * 1024 * 1024);    // 16 MB (phase B, over xl)
  unsigned short* ao = (unsigned short*)flex;            // 16 MB (phase C, over xv)

  dim3 blk(256);
  // Weight prep (x8 quirk folded into Wq, exact).
  transpose_split_f16<<<dim3(1, 16, 16), blk, 0, stream>>>(Wq, Wqk_hi, Wqk_lo, E_, D_, 8.0f);
  transpose_split_f16<<<dim3(1, 16, 16), blk, 0, stream>>>(Wk, Wqk_hi + WSZ, Wqk_lo + WSZ, E_, D_, 1.0f);
  transpose_convert<<<dim3(1, 16, 16), blk, 0, stream>>>(Wv, Wvt, E_, D_, 1.0f);
  transpose_convert<<<dim3(16, 16, 1), blk, 0, stream>>>(Wo, Wot, E_, E_, 1.0f);
  // Q projection (pre-split once, then wide GEMM).
  prep_split<<<dim3(4096), blk, 0, stream>>>(q, xh, xl);
  proj_qk2<<<dim3(64, 8), blk, 0, stream>>>(xh, xl, Wqk_hi, Wqk_lo, qk_hi, qk_lo);
  // K projection (reuses xh/xl buffers).
  prep_split<<<dim3(4096), blk, 0, stream>>>(k, xh, xl);
  proj_qk2<<<dim3(64, 8), blk, 0, stream>>>(xh, xl, Wqk_hi + WSZ, Wqk_lo + WSZ,
                                            qk_hi + NBH, qk_lo + NBH);
  // V projection (bf16), output transposed vht[b][h][d][s].
  prep_bf16<<<dim3(4096), blk, 0, stream>>>(v, xv);
  proj_v2<<<dim3(64, 8), blk, 0, stream>>>(xv, Wvt, vht);
  // Attention (paired q-tiles: block x handles q-tiles x and 15-x).
  attn_kernel<<<dim3(S_ / 256, H_, B_), blk, 0, stream>>>(
      qk_hi, qk_lo, qk_hi + NBH, qk_lo + NBH, vht, ao);
  // Output projection.
  out_gemm2<<<dim3(64, 8), blk, 0, stream>>>(ao, Wot, (float*)d_out);
}

// Round 8
// 485.895 us; speedup vs baseline: 1.8079x; 1.0264x over previous
//
#include <hip/hip_runtime.h>
#include <hip/hip_bf16.h>

#define B_ 4
#define S_ 2048
#define E_ 1024
#define H_ 16
#define D_ 64

typedef _Float16 f16;
typedef __attribute__((ext_vector_type(4))) float f32x4;
typedef __attribute__((ext_vector_type(8))) short bf16x8;
typedef __attribute__((ext_vector_type(8))) unsigned short u16x8;
typedef __attribute__((ext_vector_type(8))) _Float16 f16x8;
typedef __attribute__((ext_vector_type(4))) float float4v;

__device__ __forceinline__ unsigned short f2bf(float f) {
  union { float f; unsigned int u; } x; x.f = f;
  unsigned int u = x.u;
  u = (u + 0x7FFFu + ((u >> 16) & 1u)) >> 16;
  return (unsigned short)u;
}

#define MFMA_BF(a, b, c) __builtin_amdgcn_mfma_f32_16x16x32_bf16((a), (b), (c), 0, 0, 0)
#define MFMA_F16(a, b, c) __builtin_amdgcn_mfma_f32_16x16x32_f16((a), (b), (c), 0, 0, 0)

// Async global->LDS, 16B per lane; LDS dest = wave-uniform base + lane*16.
#define GLDS16(g, s) __builtin_amdgcn_global_load_lds( \
    (const __attribute__((address_space(1))) void*)(g), \
    (__attribute__((address_space(3))) void*)(s), 16, 0, 0)

// fp32 [z][R][C] -> bf16 [z][C][R]
__global__ __launch_bounds__(256)
void transpose_convert(const float* __restrict__ src, unsigned short* __restrict__ dst,
                       int R, int C, float scale) {
  __shared__ unsigned short tile[64][65];
  const int rb = blockIdx.y * 64;
  const int cb = blockIdx.x * 64;
  const size_t mo = (size_t)blockIdx.z * (size_t)R * (size_t)C;
  const int t = threadIdx.x;
  const int r = t >> 2;
  const int c0 = (t & 3) * 16;
  const float* sp = src + mo + (size_t)(rb + r) * C + cb + c0;
#pragma unroll
  for (int j = 0; j < 16; j += 4) {
    float4v vv = *(const float4v*)(sp + j);
    tile[r][c0 + j + 0] = f2bf(vv[0] * scale);
    tile[r][c0 + j + 1] = f2bf(vv[1] * scale);
    tile[r][c0 + j + 2] = f2bf(vv[2] * scale);
    tile[r][c0 + j + 3] = f2bf(vv[3] * scale);
  }
  __syncthreads();
  u16x8 w0, w1;
#pragma unroll
  for (int j = 0; j < 8; ++j) w0[j] = tile[c0 + j][r];
#pragma unroll
  for (int j = 0; j < 8; ++j) w1[j] = tile[c0 + 8 + j][r];
  unsigned short* dp = dst + mo + (size_t)(cb + r) * R + rb + c0;
  *(u16x8*)(dp) = w0;
  *(u16x8*)(dp + 8) = w1;
}

// fp32 [z][R][C] -> f16 hi/lo [z][C][R] (2-way split, ~23-bit effective)
__global__ __launch_bounds__(256)
void transpose_split_f16(const float* __restrict__ src, f16* __restrict__ dhi,
                         f16* __restrict__ dlo, int R, int C, float scale) {
  __shared__ float tile[64][65];
  const int rb = blockIdx.y * 64;
  const int cb = blockIdx.x * 64;
  const size_t mo = (size_t)blockIdx.z * (size_t)R * (size_t)C;
  const int t = threadIdx.x;
  const int r = t >> 2;
  const int c0 = (t & 3) * 16;
  const float* sp = src + mo + (size_t)(rb + r) * C + cb + c0;
#pragma unroll
  for (int j = 0; j < 16; j += 4) {
    float4v vv = *(const float4v*)(sp + j);
    tile[r][c0 + j + 0] = vv[0] * scale;
    tile[r][c0 + j + 1] = vv[1] * scale;
    tile[r][c0 + j + 2] = vv[2] * scale;
    tile[r][c0 + j + 3] = vv[3] * scale;
  }
  __syncthreads();
  f16x8 h0, h1, l0, l1;
#pragma unroll
  for (int j = 0; j < 8; ++j) {
    float x = tile[c0 + j][r];
    f16 hi = (f16)x;
    h0[j] = hi; l0[j] = (f16)(x - (float)hi);
  }
#pragma unroll
  for (int j = 0; j < 8; ++j) {
    float x = tile[c0 + 8 + j][r];
    f16 hi = (f16)x;
    h1[j] = hi; l1[j] = (f16)(x - (float)hi);
  }
  const size_t o = mo + (size_t)(cb + r) * R + rb + c0;
  *(f16x8*)(dhi + o) = h0; *(f16x8*)(dhi + o + 8) = h1;
  *(f16x8*)(dlo + o) = l0; *(f16x8*)(dlo + o + 8) = l1;
}

// fp32 -> f16 hi/lo, flat; 8 elems/thread
__global__ __launch_bounds__(256)
void prep_split(const float* __restrict__ x, f16* __restrict__ xh, f16* __restrict__ xl) {
  const size_t i = ((size_t)blockIdx.x * 256 + threadIdx.x) * 8;
  float4v a = *(const float4v*)(x + i);
  float4v b = *(const float4v*)(x + i + 4);
  f16x8 h, lo;
#pragma unroll
  for (int j = 0; j < 4; ++j) {
    f16 hi = (f16)a[j]; h[j] = hi; lo[j] = (f16)(a[j] - (float)hi);
  }
#pragma unroll
  for (int j = 0; j < 4; ++j) {
    f16 hi = (f16)b[j]; h[4 + j] = hi; lo[4 + j] = (f16)(b[j] - (float)hi);
  }
  *(f16x8*)(xh + i) = h;
  *(f16x8*)(xl + i) = lo;
}

// fp32 -> bf16, flat; 8 elems/thread
__global__ __launch_bounds__(256)
void prep_bf16(const float* __restrict__ x, unsigned short* __restrict__ xo) {
  const size_t i = ((size_t)blockIdx.x * 256 + threadIdx.x) * 8;
  float4v a = *(const float4v*)(x + i);
  float4v b = *(const float4v*)(x + i + 4);
  u16x8 o;
#pragma unroll
  for (int j = 0; j < 4; ++j) { o[j] = f2bf(a[j]); o[4 + j] = f2bf(b[j]); }
  *(u16x8*)(xo + i) = o;
}

// Q/K projection v3: m97 structure — global_load_lds(16B) into LINEAR LDS
// tiles, single-buffered, 2 barriers per K-step. 3-term split-f16 MFMA.
// out: [b][h][s][d] f16 hi/lo (n = h*64+d).
__global__ __launch_bounds__(256, 2)
void proj_qk3(const f16* __restrict__ xh, const f16* __restrict__ xl,
              const f16* __restrict__ Wh, const f16* __restrict__ Wl,
              f16* __restrict__ out_hi, f16* __restrict__ out_lo) {
  __shared__ f16 Ah[128 * 32], Al[128 * 32], Bh[128 * 32], Bl[128 * 32];
  const int t = threadIdx.x;
  const int m0 = blockIdx.x * 128, n0 = blockIdx.y * 128;
  const int w = t >> 6, l = t & 63, lr = l & 15, lg = l >> 4;
  const int wm = (w & 1) * 64, wn = (w >> 1) * 64;
  // Staging: chunk = w*2+j covers rows [chunk*16, chunk*16+16); lane l ->
  // row chunk*16 + (l>>2), col (l&3)*8 f16 (4 lanes x 16B = one 64B row).
  const int srow = w * 32 + (l >> 2);       // + j*16
  const int scol = (l & 3) * 8;

  f32x4 acc[4][4];
#pragma unroll
  for (int im = 0; im < 4; ++im)
#pragma unroll
    for (int in = 0; in < 4; ++in) acc[im][in] = (f32x4){0.f, 0.f, 0.f, 0.f};

  for (int k0 = 0; k0 < 1024; k0 += 32) {
#pragma unroll
    for (int j = 0; j < 2; ++j) {
      const size_t ga = (size_t)(m0 + srow + j * 16) * 1024 + scol + k0;
      const size_t gb = (size_t)(n0 + srow + j * 16) * 1024 + scol + k0;
      const int lo = (w * 32 + j * 16) * 32;
      GLDS16(xh + ga, &Ah[lo]);
      GLDS16(xl + ga, &Al[lo]);
      GLDS16(Wh + gb, &Bh[lo]);
      GLDS16(Wl + gb, &Bl[lo]);
    }
    __syncthreads();  // drains vmcnt (compiler) + publishes LDS

    f16x8 afh[4], afl[4], bfh[4], bfl[4];
#pragma unroll
    for (int im = 0; im < 4; ++im) {
      afh[im] = *(const f16x8*)&Ah[(wm + im * 16 + lr) * 32 + lg * 8];
      afl[im] = *(const f16x8*)&Al[(wm + im * 16 + lr) * 32 + lg * 8];
    }
#pragma unroll
    for (int in = 0; in < 4; ++in) {
      bfh[in] = *(const f16x8*)&Bh[(wn + in * 16 + lr) * 32 + lg * 8];
      bfl[in] = *(const f16x8*)&Bl[(wn + in * 16 + lr) * 32 + lg * 8];
    }
#pragma unroll
    for (int im = 0; im < 4; ++im)
#pragma unroll
      for (int in = 0; in < 4; ++in) {
        acc[im][in] = MFMA_F16(afh[im], bfh[in], acc[im][in]);
        acc[im][in] = MFMA_F16(afh[im], bfl[in], acc[im][in]);
        acc[im][in] = MFMA_F16(afl[im], bfh[in], acc[im][in]);
      }
    __syncthreads();  // readers done before next stage overwrites
  }

  const int b = m0 >> 11, s0b = m0 & 2047;
#pragma unroll
  for (int im = 0; im < 4; ++im)
#pragma unroll
    for (int in = 0; in < 4; ++in)
#pragma unroll
      for (int rr = 0; rr < 4; ++rr) {
        const int srw = s0b + wm + im * 16 + lg * 4 + rr;
        const int n = n0 + wn + in * 16 + lr;
        const int h = n >> 6, d = n & 63;
        const size_t o = (((size_t)b * H_ + h) * S_ + srw) * D_ + d;
        const float x = acc[im][in][rr];
        const f16 hi = (f16)x;
        out_hi[o] = hi;
        out_lo[o] = (f16)(x - (float)hi);
      }
}

// V projection v3: m97 structure, bf16; epilogue transposes to vht[b][h][d][s].
__global__ __launch_bounds__(256, 2)
void proj_v3(const unsigned short* __restrict__ xv, const unsigned short* __restrict__ Wv,
             f16* __restrict__ vht) {
  __shared__ short smem[17408];  // GEMM: As(8KB)+Bs(8KB) linear; epi: Td[128][136] f16
  unsigned short* As = (unsigned short*)smem;
  unsigned short* Bs = As + 128 * 32;
  const int t = threadIdx.x;
  const int m0 = blockIdx.x * 128, n0 = blockIdx.y * 128;
  const int w = t >> 6, l = t & 63, lr = l & 15, lg = l >> 4;
  const int wm = (w & 1) * 64, wn = (w >> 1) * 64;
  const int srow = w * 32 + (l >> 2);
  const int scol = (l & 3) * 8;

  f32x4 acc[4][4];
#pragma unroll
  for (int im = 0; im < 4; ++im)
#pragma unroll
    for (int in = 0; in < 4; ++in) acc[im][in] = (f32x4){0.f, 0.f, 0.f, 0.f};

  for (int k0 = 0; k0 < 1024; k0 += 32) {
#pragma unroll
    for (int j = 0; j < 2; ++j) {
      const size_t ga = (size_t)(m0 + srow + j * 16) * 1024 + scol + k0;
      const size_t gb = (size_t)(n0 + srow + j * 16) * 1024 + scol + k0;
      const int lo = (w * 32 + j * 16) * 32;
      GLDS16(xv + ga, &As[lo]);
      GLDS16(Wv + gb, &Bs[lo]);
    }
    __syncthreads();

    bf16x8 af[4], bf[4];
#pragma unroll
    for (int im = 0; im < 4; ++im)
      af[im] = *(const bf16x8*)&As[(wm + im * 16 + lr) * 32 + lg * 8];
#pragma unroll
    for (int in = 0; in < 4; ++in)
      bf[in] = *(const bf16x8*)&Bs[(wn + in * 16 + lr) * 32 + lg * 8];
#pragma unroll
    for (int im = 0; im < 4; ++im)
#pragma unroll
      for (int in = 0; in < 4; ++in)
        acc[im][in] = MFMA_BF(af[im], bf[in], acc[im][in]);
    __syncthreads();
  }

  // Transpose epilogue: Td[n][s] (stride 136), then coalesced f16 writes.
  f16* Td = (f16*)smem;
#pragma unroll
  for (int im = 0; im < 4; ++im)
#pragma unroll
    for (int in = 0; in < 4; ++in)
#pragma unroll
      for (int rr = 0; rr < 4; ++rr) {
        const int srw = wm + im * 16 + lg * 4 + rr;    // 0..127
        const int ncol = wn + in * 16 + lr;            // 0..127
        Td[ncol * 136 + srw] = (f16)acc[im][in][rr];
      }
  __syncthreads();
  const int n = t >> 1, sc2 = (t & 1) * 64;
  const int b = m0 >> 11, s0b = m0 & 2047;
  const int h = (n0 + n) >> 6, d = (n0 + n) & 63;
  f16* vp = vht + (((size_t)b * H_ + h) * D_ + d) * S_ + s0b + sc2;
#pragma unroll
  for (int j = 0; j < 8; ++j)
    *(f16x8*)(vp + j * 8) = *(const f16x8*)&Td[n * 136 + sc2 + j * 8];
}

// Output projection v3: m97 structure, bf16 GEMM, fp32 output.
__global__ __launch_bounds__(256, 2)
void out_gemm3(const unsigned short* __restrict__ A, const unsigned short* __restrict__ Bt,
               float* __restrict__ Cout) {
  __shared__ unsigned short As[128 * 32], Bs[128 * 32];
  const int t = threadIdx.x;
  const int m0 = blockIdx.x * 128, n0 = blockIdx.y * 128;
  const int w = t >> 6, l = t & 63, lr = l & 15, lg = l >> 4;
  const int wm = (w & 1) * 64, wn = (w >> 1) * 64;
  const int srow = w * 32 + (l >> 2);
  const int scol = (l & 3) * 8;

  f32x4 acc[4][4];
#pragma unroll
  for (int im = 0; im < 4; ++im)
#pragma unroll
    for (int in = 0; in < 4; ++in) acc[im][in] = (f32x4){0.f, 0.f, 0.f, 0.f};

  for (int k0 = 0; k0 < 1024; k0 += 32) {
#pragma unroll
    for (int j = 0; j < 2; ++j) {
      const size_t ga = (size_t)(m0 + srow + j * 16) * 1024 + scol + k0;
      const size_t gb = (size_t)(n0 + srow + j * 16) * 1024 + scol + k0;
      const int lo = (w * 32 + j * 16) * 32;
      GLDS16(A + ga, &As[lo]);
      GLDS16(Bt + gb, &Bs[lo]);
    }
    __syncthreads();

    bf16x8 af[4], bf[4];
#pragma unroll
    for (int im = 0; im < 4; ++im)
      af[im] = *(const bf16x8*)&As[(wm + im * 16 + lr) * 32 + lg * 8];
#pragma unroll
    for (int in = 0; in < 4; ++in)
      bf[in] = *(const bf16x8*)&Bs[(wn + in * 16 + lr) * 32 + lg * 8];
#pragma unroll
    for (int im = 0; im < 4; ++im)
#pragma unroll
      for (int in = 0; in < 4; ++in)
        acc[im][in] = MFMA_BF(af[im], bf[in], acc[im][in]);
    __syncthreads();
  }

#pragma unroll
  for (int im = 0; im < 4; ++im)
#pragma unroll
    for (int in = 0; in < 4; ++in)
#pragma unroll
      for (int rr = 0; rr < 4; ++rr) {
        const int row = m0 + wm + im * 16 + lg * 4 + rr;
        const int col = n0 + wn + in * 16 + lr;
        Cout[(size_t)row * 1024 + col] = acc[im][in][rr];
      }
}

// Causal flash attention v3 (unchanged): paired q-tiles (x, 15-x),
// reg-prefetch double-buffered K/V staging, XOR-swizzled LDS.
__global__ __launch_bounds__(256, 2)
void attn_kernel(const f16* __restrict__ qhh, const f16* __restrict__ qhl,
                 const f16* __restrict__ khh, const f16* __restrict__ khl,
                 const f16* __restrict__ vht, unsigned short* __restrict__ ao) {
  __shared__ f16 Ksh[2][64 * 64];
  __shared__ f16 Ksl[2][64 * 64];
  __shared__ f16 Vts[2][64 * 64];
  __shared__ f16 Pls[4][32 * 64];
  const int t = threadIdx.x;
  const int b = blockIdx.z, h = blockIdx.y;
  const int w = t >> 6, l = t & 63, lr = l & 15, lg = l >> 4;
  const size_t bh = ((size_t)b * H_ + h) * S_;
  const size_t bhD = ((size_t)b * H_ + h) * D_;
  const int cr0 = t >> 3, cch = t & 7;
  const int cr1 = (t + 256) >> 3;
  const int coff = (cch * 16);

#pragma unroll
  for (int ph = 0; ph < 2; ++ph) {
    const int qt = ph ? (15 - (int)blockIdx.x) : (int)blockIdx.x;
    const int q0 = qt * 128;

    f16x8 qfh[2][2], qfl[2][2];
#pragma unroll
    for (int i = 0; i < 2; ++i) {
      const size_t qo = (bh + q0 + w * 32 + i * 16 + lr) * D_;
#pragma unroll
      for (int hf = 0; hf < 2; ++hf) {
        qfh[i][hf] = *(const f16x8*)(qhh + qo + hf * 32 + lg * 8);
        qfl[i][hf] = *(const f16x8*)(qhl + qo + hf * 32 + lg * 8);
      }
    }

    f32x4 acc[2][4];
#pragma unroll
    for (int i = 0; i < 2; ++i)
#pragma unroll
      for (int c = 0; c < 4; ++c) acc[i][c] = (f32x4){0.f, 0.f, 0.f, 0.f};
    float mx[2][4], ls[2][4];
#pragma unroll
    for (int i = 0; i < 2; ++i)
#pragma unroll
      for (int r = 0; r < 4; ++r) { mx[i][r] = -3.0e38f; ls[i][r] = 0.f; }

    const int wmax = q0 + w * 32 + 31;
    const int nkt = 2 * qt + 2;
    int cur = 0;

    {
      const f16* kbh = khh + bh * D_;
      const f16* kbl = khl + bh * D_;
      const f16* vb = vht + bhD * S_;
      f16x8 a0 = *(const f16x8*)(kbh + cr0 * 64 + cch * 8);
      f16x8 a1 = *(const f16x8*)(kbh + cr1 * 64 + cch * 8);
      f16x8 b0 = *(const f16x8*)(kbl + cr0 * 64 + cch * 8);
      f16x8 b1 = *(const f16x8*)(kbl + cr1 * 64 + cch * 8);
      f16x8 c0 = *(const f16x8*)(vb + (size_t)cr0 * S_ + cch * 8);
      f16x8 c1 = *(const f16x8*)(vb + (size_t)cr1 * S_ + cch * 8);
      const int o0 = coff ^ ((cr0 & 7) << 4);
      const int o1 = coff ^ ((cr1 & 7) << 4);
      *(f16x8*)((char*)Ksh[0] + cr0 * 128 + o0) = a0;
      *(f16x8*)((char*)Ksh[0] + cr1 * 128 + o1) = a1;
      *(f16x8*)((char*)Ksl[0] + cr0 * 128 + o0) = b0;
      *(f16x8*)((char*)Ksl[0] + cr1 * 128 + o1) = b1;
      *(f16x8*)((char*)Vts[0] + cr0 * 128 + o0) = c0;
      *(f16x8*)((char*)Vts[0] + cr1 * 128 + o1) = c1;
    }

    for (int kt = 0; kt < nkt; ++kt) {
      const int kt0 = kt * 64;
      __syncthreads();

      const bool pf = (kt + 1 < nkt);
      f16x8 ra0, ra1, rb0, rb1, rc0, rc1;
      if (pf) {
        const int n0 = kt0 + 64;
        const f16* kbh = khh + (bh + n0) * D_;
        const f16* kbl = khl + (bh + n0) * D_;
        const f16* vb = vht + bhD * S_ + n0;
        ra0 = *(const f16x8*)(kbh + cr0 * 64 + cch * 8);
        ra1 = *(const f16x8*)(kbh + cr1 * 64 + cch * 8);
        rb0 = *(const f16x8*)(kbl + cr0 * 64 + cch * 8);
        rb1 = *(const f16x8*)(kbl + cr1 * 64 + cch * 8);
        rc0 = *(const f16x8*)(vb + (size_t)cr0 * S_ + cch * 8);
        rc1 = *(const f16x8*)(vb + (size_t)cr1 * S_ + cch * 8);
      }

      if (kt0 <= wmax) {
        f32x4 sc[2][4];
#pragma unroll
        for (int n = 0; n < 4; ++n) {
          const int krow = n * 16 + lr;
          const int sw = (krow & 7) << 4;
          const char* kb = (const char*)Ksh[cur] + krow * 128;
          const char* kbl2 = (const char*)Ksl[cur] + krow * 128;
          f16x8 kh0 = *(const f16x8*)(kb + ((lg * 16) ^ sw));
          f16x8 kh1 = *(const f16x8*)(kb + ((64 + lg * 16) ^ sw));
          f16x8 kl0 = *(const f16x8*)(kbl2 + ((lg * 16) ^ sw));
          f16x8 kl1 = *(const f16x8*)(kbl2 + ((64 + lg * 16) ^ sw));
#pragma unroll
          for (int i = 0; i < 2; ++i) {
            f32x4 z = (f32x4){0.f, 0.f, 0.f, 0.f};
            z = MFMA_F16(qfh[i][0], kh0, z);
            z = MFMA_F16(qfh[i][1], kh1, z);
            z = MFMA_F16(qfh[i][0], kl0, z);
            z = MFMA_F16(qfh[i][1], kl1, z);
            z = MFMA_F16(qfl[i][0], kh0, z);
            z = MFMA_F16(qfl[i][1], kh1, z);
            sc[i][n] = z;
          }
        }

#pragma unroll
        for (int i = 0; i < 2; ++i) {
          const int qbase = q0 + w * 32 + i * 16;
          const bool full = (kt0 + 63 <= qbase);
#pragma unroll
          for (int r = 0; r < 4; ++r) {
            const int qrow = qbase + lg * 4 + r;
            float v0 = sc[i][0][r], v1 = sc[i][1][r], v2 = sc[i][2][r], v3 = sc[i][3][r];
            if (!full) {
              v0 = (kt0 + 0 + lr <= qrow) ? v0 : -3.0e38f;
              v1 = (kt0 + 16 + lr <= qrow) ? v1 : -3.0e38f;
              v2 = (kt0 + 32 + lr <= qrow) ? v2 : -3.0e38f;
              v3 = (kt0 + 48 + lr <= qrow) ? v3 : -3.0e38f;
            }
            float tm = fmaxf(fmaxf(v0, v1), fmaxf(v2, v3));
            tm = fmaxf(tm, __shfl_xor(tm, 1));
            tm = fmaxf(tm, __shfl_xor(tm, 2));
            tm = fmaxf(tm, __shfl_xor(tm, 4));
            tm = fmaxf(tm, __shfl_xor(tm, 8));
            const float mn = fmaxf(mx[i][r], tm);
            const float corr = __expf(mx[i][r] - mn);
            mx[i][r] = mn;
            float p0 = __expf(v0 - mn), p1 = __expf(v1 - mn);
            float p2 = __expf(v2 - mn), p3 = __expf(v3 - mn);
            float ps = (p0 + p1) + (p2 + p3);
            ps += __shfl_xor(ps, 1);
            ps += __shfl_xor(ps, 2);
            ps += __shfl_xor(ps, 4);
            ps += __shfl_xor(ps, 8);
            ls[i][r] = ls[i][r] * corr + ps;
#pragma unroll
            for (int c = 0; c < 4; ++c) acc[i][c][r] *= corr;
            const int qi = i * 16 + lg * 4 + r;
            char* pb = (char*)&Pls[w][0] + qi * 128;
            const int sw2 = (qi & 7) << 4;
            *(f16*)(pb + ((0 + lr * 2) ^ sw2)) = (f16)p0;
            *(f16*)(pb + ((32 + lr * 2) ^ sw2)) = (f16)p1;
            *(f16*)(pb + ((64 + lr * 2) ^ sw2)) = (f16)p2;
            *(f16*)(pb + ((96 + lr * 2) ^ sw2)) = (f16)p3;
          }
        }

#pragma unroll
        for (int ks = 0; ks < 2; ++ks) {
          const int co = (ks * 64 + lg * 16);
          f16x8 pf0 = *(const f16x8*)((const char*)&Pls[w][0] + lr * 128 + (co ^ ((lr & 7) << 4)));
          f16x8 pf1 = *(const f16x8*)((const char*)&Pls[w][0] + (16 + lr) * 128 + (co ^ ((lr & 7) << 4)));
#pragma unroll
          for (int c = 0; c < 4; ++c) {
            const int vr = c * 16 + lr;
            f16x8 vf = *(const f16x8*)((const char*)Vts[cur] + vr * 128 + (co ^ ((vr & 7) << 4)));
            acc[0][c] = MFMA_F16(pf0, vf, acc[0][c]);
            acc[1][c] = MFMA_F16(pf1, vf, acc[1][c]);
          }
        }
      }

      __syncthreads();
      if (pf) {
        const int nb = cur ^ 1;
        const int o0 = coff ^ ((cr0 & 7) << 4);
        const int o1 = coff ^ ((cr1 & 7) << 4);
        *(f16x8*)((char*)Ksh[nb] + cr0 * 128 + o0) = ra0;
        *(f16x8*)((char*)Ksh[nb] + cr1 * 128 + o1) = ra1;
        *(f16x8*)((char*)Ksl[nb] + cr0 * 128 + o0) = rb0;
        *(f16x8*)((char*)Ksl[nb] + cr1 * 128 + o1) = rb1;
        *(f16x8*)((char*)Vts[nb] + cr0 * 128 + o0) = rc0;
        *(f16x8*)((char*)Vts[nb] + cr1 * 128 + o1) = rc1;
      }
      cur ^= 1;
    }

#pragma unroll
    for (int i = 0; i < 2; ++i)
#pragma unroll
      for (int r = 0; r < 4; ++r) {
        const float inv = 1.0f / ls[i][r];
        const size_t s = q0 + w * 32 + i * 16 + lg * 4 + r;
        const size_t o = ((size_t)b * S_ + s) * (H_ * D_) + (size_t)h * D_;
#pragma unroll
        for (int c = 0; c < 4; ++c)
          ao[o + c * 16 + lr] = f2bf(acc[i][c][r] * inv);
      }
  }
}

extern "C" void kernel_launch(void* const* d_in, const int* in_sizes, int n_in,
                              void* d_out, int out_size, void* d_ws, size_t ws_size,
                              hipStream_t stream) {
  const float* q = (const float*)d_in[0];
  const float* k = (const float*)d_in[1];
  const float* v = (const float*)d_in[2];
  const float* Wq = (const float*)d_in[3];
  const float* Wk = (const float*)d_in[4];
  const float* Wv = (const float*)d_in[5];
  const float* Wo = (const float*)d_in[6];

  const size_t NBH = (size_t)B_ * H_ * S_ * D_;   // 8388608
  const size_t WSZ = (size_t)H_ * D_ * E_;        // 1048576

  // ws layout (108 MB peak):
  // [0,12M): weights; [12M,76M): qk_hi/lo; [76M,108M): flex (xh/xl -> xv/vht -> ao)
  char* wsb = (char*)d_ws;
  f16* Wqk_hi = (f16*)wsb;                               // 4 MB
  f16* Wqk_lo = Wqk_hi + 2 * WSZ;                        // 4 MB
  unsigned short* Wvt = (unsigned short*)(Wqk_lo + 2 * WSZ);  // 2 MB
  unsigned short* Wot = Wvt + WSZ;                       // 2 MB
  f16* qk_hi = (f16*)(wsb + (size_t)12 * 1024 * 1024);   // 32 MB
  f16* qk_lo = qk_hi + 2 * NBH;                          // 32 MB
  char* flex = wsb + (size_t)76 * 1024 * 1024;
  f16* xh = (f16*)flex;                                  // 16 MB (phase A)
  f16* xl = (f16*)(flex + (size_t)16 * 1024 * 1024);     // 16 MB (phase A)
  unsigned short* xv = (unsigned short*)flex;            // 16 MB (phase B, over xh)
  f16* vht = (f16*)(flex + (size_t)16 * 1024 * 1024);    // 16 MB (phase B, over xl)
  unsigned short* ao = (unsigned short*)flex;            // 16 MB (phase C, over xv)

  dim3 blk(256);
  // Weight prep (x8 quirk folded into Wq, exact).
  transpose_split_f16<<<dim3(1, 16, 16), blk, 0, stream>>>(Wq, Wqk_hi, Wqk_lo, E_, D_, 8.0f);
  transpose_split_f16<<<dim3(1, 16, 16), blk, 0, stream>>>(Wk, Wqk_hi + WSZ, Wqk_lo + WSZ, E_, D_, 1.0f);
  transpose_convert<<<dim3(1, 16, 16), blk, 0, stream>>>(Wv, Wvt, E_, D_, 1.0f);
  transpose_convert<<<dim3(16, 16, 1), blk, 0, stream>>>(Wo, Wot, E_, E_, 1.0f);
  // Q projection (pre-split once, then wide GEMM).
  prep_split<<<dim3(4096), blk, 0, stream>>>(q, xh, xl);
  proj_qk3<<<dim3(64, 8), blk, 0, stream>>>(xh, xl, Wqk_hi, Wqk_lo, qk_hi, qk_lo);
  // K projection (reuses xh/xl buffers).
  prep_split<<<dim3(4096), blk, 0, stream>>>(k, xh, xl);
  proj_qk3<<<dim3(64, 8), blk, 0, stream>>>(xh, xl, Wqk_hi + WSZ, Wqk_lo + WSZ,
                                            qk_hi + NBH, qk_lo + NBH);
  // V projection (bf16), output transposed vht[b][h][d][s].
  prep_bf16<<<dim3(4096), blk, 0, stream>>>(v, xv);
  proj_v3<<<dim3(64, 8), blk, 0, stream>>>(xv, Wvt, vht);
  // Attention (paired q-tiles: block x handles q-tiles x and 15-x).
  attn_kernel<<<dim3(S_ / 256, H_, B_), blk, 0, stream>>>(
      qk_hi, qk_lo, qk_hi + NBH, qk_lo + NBH, vht, ao);
  // Output projection.
  out_gemm3<<<dim3(64, 8), blk, 0, stream>>>(ao, Wot, (float*)d_out);
}